// Round 2
// baseline (3576.529 us; speedup 1.0000x reference)
//
#include <hip/hip_runtime.h>
#include <cstdint>
#include <cstddef>

#define BB 1024
#define AA 200
#define DD 128
#define HH 8
#define N3 384

typedef unsigned short u16;
typedef unsigned int u32;

__device__ __forceinline__ float bf2f(u16 v){ return __uint_as_float(((u32)v) << 16); }
__device__ __forceinline__ u16 f2bf(float f){
  u32 u = __float_as_uint(f);
  u32 r = u + 0x7fffu + ((u >> 16) & 1u);
  return (u16)(r >> 16);
}
__device__ __forceinline__ void unpack8(uint4 v, float* f){
  f[0] = __uint_as_float(v.x << 16); f[1] = __uint_as_float(v.x & 0xffff0000u);
  f[2] = __uint_as_float(v.y << 16); f[3] = __uint_as_float(v.y & 0xffff0000u);
  f[4] = __uint_as_float(v.z << 16); f[5] = __uint_as_float(v.z & 0xffff0000u);
  f[6] = __uint_as_float(v.w << 16); f[7] = __uint_as_float(v.w & 0xffff0000u);
}

// ---------------- K0: copy old_action to out (as float) + build rank ----------------
__global__ void k_act_rank(const int* __restrict__ oa, float* __restrict__ out0,
                           int* __restrict__ rank){
  int m = blockIdx.x * 256 + threadIdx.x;
  if (m >= BB*AA) return;
  int v = oa[m];
  out0[m] = (float)v;
  int b = m / AA;
  int j = m - b*AA;
  rank[b*AA + v] = j;
}

// ---------------- K1: fixed_ctx = mean_a(E[b]) @ W_fixed ----------------
__global__ void k_fixed(const float* __restrict__ E, const float* __restrict__ Wf,
                        float* __restrict__ fixedc){
  int b = blockIdx.x;
  int d = threadIdx.x;              // 128 threads
  __shared__ float ge[DD];
  const float* Eb = E + (size_t)b*AA*DD;
  float s = 0.f;
  for (int a = 0; a < AA; ++a) s += Eb[a*DD + d];
  ge[d] = s * (1.0f/AA);
  __syncthreads();
  float acc = 0.f;
  for (int k = 0; k < DD; ++k) acc = fmaf(ge[k], Wf[k*DD + d], acc);
  fixedc[b*DD + d] = acc;
}

// ---------------- K2a: proj = E @ W_node  (M=B*A, K=128, N=384) -> bf16 ----------------
__global__ __launch_bounds__(256) void k_proj(const float* __restrict__ E,
                                              const float* __restrict__ Wn,
                                              u16* __restrict__ proj){
  __shared__ float Ast[128][68];   // transposed A tile [k][row]
  __shared__ float Bs[128][68];    // [k][col]
  int t = threadIdx.x;
  int m0 = blockIdx.x * 64;
  int n0 = blockIdx.y * 64;
  for (int p = 0; p < 8; ++p){
    int idx = t + p*256;
    int row = idx >> 5, c4 = (idx & 31) << 2;
    float4 ev = *(const float4*)(E + (size_t)(m0+row)*DD + c4);
    Ast[c4+0][row] = ev.x; Ast[c4+1][row] = ev.y;
    Ast[c4+2][row] = ev.z; Ast[c4+3][row] = ev.w;
  }
  for (int p = 0; p < 8; ++p){
    int idx = t + p*256;
    int k = idx >> 4, c4 = (idx & 15) << 2;
    *(float4*)&Bs[k][c4] = *(const float4*)(Wn + (size_t)k*N3 + n0 + c4);
  }
  __syncthreads();
  int tx = t & 15, ty = t >> 4;
  float acc[4][4] = {};
  for (int k = 0; k < 128; ++k){
    float4 av = *(const float4*)&Ast[k][ty*4];
    float4 bv = *(const float4*)&Bs[k][tx*4];
    float a_[4] = {av.x, av.y, av.z, av.w};
    float b_[4] = {bv.x, bv.y, bv.z, bv.w};
    #pragma unroll
    for (int r = 0; r < 4; ++r)
      #pragma unroll
      for (int cc = 0; cc < 4; ++cc) acc[r][cc] = fmaf(a_[r], b_[cc], acc[r][cc]);
  }
  #pragma unroll
  for (int r = 0; r < 4; ++r){
    int row = m0 + ty*4 + r;
    ushort4 o;
    o.x = f2bf(acc[r][0]); o.y = f2bf(acc[r][1]);
    o.z = f2bf(acc[r][2]); o.w = f2bf(acc[r][3]);
    *(ushort4*)(proj + (size_t)row*N3 + n0 + tx*4) = o;
  }
}

// ---------------- K2b: query = fixed_ctx + gather(E,prev) @ W_step -> bf16 ----------------
__global__ __launch_bounds__(256) void k_query(const float* __restrict__ E,
                                               const int* __restrict__ oa,
                                               const float* __restrict__ Wp,
                                               const float* __restrict__ Ws,
                                               const float* __restrict__ fixedc,
                                               u16* __restrict__ qhg){
  __shared__ float Ast[128][68];
  __shared__ float Bs[128][68];
  int t = threadIdx.x;
  int m0 = blockIdx.x * 64;
  int n0 = blockIdx.y * 64;
  for (int p = 0; p < 8; ++p){
    int idx = t + p*256;
    int row = idx >> 5, c4 = (idx & 31) << 2;
    int m = m0 + row;
    int b = m / AA, i = m - b*AA;
    const float* src = (i == 0) ? Wp : (E + (size_t)(b*AA + oa[b*AA + i - 1])*DD);
    float4 ev = *(const float4*)(src + c4);
    Ast[c4+0][row] = ev.x; Ast[c4+1][row] = ev.y;
    Ast[c4+2][row] = ev.z; Ast[c4+3][row] = ev.w;
  }
  for (int p = 0; p < 8; ++p){
    int idx = t + p*256;
    int k = idx >> 4, c4 = (idx & 15) << 2;
    *(float4*)&Bs[k][c4] = *(const float4*)(Ws + (size_t)k*DD + n0 + c4);
  }
  __syncthreads();
  int tx = t & 15, ty = t >> 4;
  float acc[4][4] = {};
  for (int k = 0; k < 128; ++k){
    float4 av = *(const float4*)&Ast[k][ty*4];
    float4 bv = *(const float4*)&Bs[k][tx*4];
    float a_[4] = {av.x, av.y, av.z, av.w};
    float b_[4] = {bv.x, bv.y, bv.z, bv.w};
    #pragma unroll
    for (int r = 0; r < 4; ++r)
      #pragma unroll
      for (int cc = 0; cc < 4; ++cc) acc[r][cc] = fmaf(a_[r], b_[cc], acc[r][cc]);
  }
  #pragma unroll
  for (int r = 0; r < 4; ++r){
    int row = m0 + ty*4 + r;
    int b = row / AA;
    ushort4 o;
    o.x = f2bf(acc[r][0] + fixedc[b*DD + n0 + tx*4 + 0]);
    o.y = f2bf(acc[r][1] + fixedc[b*DD + n0 + tx*4 + 1]);
    o.z = f2bf(acc[r][2] + fixedc[b*DD + n0 + tx*4 + 2]);
    o.w = f2bf(acc[r][3] + fixedc[b*DD + n0 + tx*4 + 3]);
    *(ushort4*)(qhg + (size_t)row*DD + n0 + tx*4) = o;
  }
}

// ---------------- K3: attention (per (b, head-quad)), all i; heads overwrite qhg ----------------
__global__ __launch_bounds__(256) void k_attn(const u16* __restrict__ proj,
                                              const int* __restrict__ rank,
                                              u16* __restrict__ qhg){
  __shared__ __align__(16) u16 KT[64*200];     // [local col (h*16+d)][a]
  __shared__ __align__(16) u16 VT[64*200];
  __shared__ __align__(16) u16 pT[4*200*8];    // [h][a][ii]
  __shared__ __align__(16) u16 qT[64*8];       // [local col][ii]
  const int b = blockIdx.x;
  const int quad = blockIdx.y;                 // heads quad*4 .. quad*4+3
  const int t = threadIdx.x;
  const int colbase = quad * 64;

  for (int idx = t; idx < 200*64; idx += 256){
    int a = idx >> 6, col = idx & 63;
    const u16* pr = proj + (size_t)(b*AA + a) * N3;
    KT[col*200 + a] = pr[colbase + col];
    VT[col*200 + a] = pr[128 + colbase + col];
  }
  int h = 0, c = 0;
  int r8i[8];
  const bool lane_on = (t < 128);
  if (lane_on){
    h = t >> 5; c = t & 31;
    if (c < 25){
      #pragma unroll
      for (int aa = 0; aa < 8; ++aa) r8i[aa] = rank[b*AA + c*8 + aa];
    }
  }
  __syncthreads();

  for (int it0 = 0; it0 < AA; it0 += 8){
    for (int idx = t; idx < 512; idx += 256){
      int ii = idx >> 6, col = idx & 63;
      qT[col*8 + ii] = qhg[(size_t)(b*AA + it0 + ii)*DD + colbase + col];
    }
    __syncthreads();

    if (lane_on){
      float s[8][8];
      if (c < 25){
        #pragma unroll
        for (int ii = 0; ii < 8; ++ii)
          #pragma unroll
          for (int aa = 0; aa < 8; ++aa) s[ii][aa] = 0.f;
        #pragma unroll
        for (int d0 = 0; d0 < 16; ++d0){
          int row = h*16 + d0;
          uint4 kv = *(const uint4*)&KT[row*200 + c*8];
          uint4 qv = *(const uint4*)&qT[row*8];
          float kf[8], qf[8];
          unpack8(kv, kf); unpack8(qv, qf);
          #pragma unroll
          for (int ii = 0; ii < 8; ++ii)
            #pragma unroll
            for (int aa = 0; aa < 8; ++aa)
              s[ii][aa] = fmaf(qf[ii], kf[aa], s[ii][aa]);
        }
        #pragma unroll
        for (int ii = 0; ii < 8; ++ii)
          #pragma unroll
          for (int aa = 0; aa < 8; ++aa){
            float v = s[ii][aa] * 0.25f;   // 1/sqrt(16)
            s[ii][aa] = (r8i[aa] < it0 + ii) ? -__builtin_inff() : v;
          }
      } else {
        #pragma unroll
        for (int ii = 0; ii < 8; ++ii)
          #pragma unroll
          for (int aa = 0; aa < 8; ++aa) s[ii][aa] = -__builtin_inff();
      }
      // masked softmax over a (group of 32 lanes = 25 active chunks)
      #pragma unroll
      for (int ii = 0; ii < 8; ++ii){
        float m = s[ii][0];
        #pragma unroll
        for (int aa = 1; aa < 8; ++aa) m = fmaxf(m, s[ii][aa]);
        #pragma unroll
        for (int off = 16; off >= 1; off >>= 1) m = fmaxf(m, __shfl_xor(m, off, 32));
        float e[8]; float sum = 0.f;
        #pragma unroll
        for (int aa = 0; aa < 8; ++aa){
          float ee = (s[ii][aa] > -1e30f) ? __expf(s[ii][aa] - m) : 0.f;
          e[aa] = ee; sum += ee;
        }
        #pragma unroll
        for (int off = 16; off >= 1; off >>= 1) sum += __shfl_xor(sum, off, 32);
        float inv = 1.0f / sum;
        #pragma unroll
        for (int aa = 0; aa < 8; ++aa) s[ii][aa] = e[aa] * inv;
      }
      if (c < 25){
        #pragma unroll
        for (int si = 0; si < 8; ++si){
          int aa = (c + si) & 7;   // rotate to spread LDS banks
          uint4 w;
          w.x = (u32)f2bf(s[0][aa]) | ((u32)f2bf(s[1][aa]) << 16);
          w.y = (u32)f2bf(s[2][aa]) | ((u32)f2bf(s[3][aa]) << 16);
          w.z = (u32)f2bf(s[4][aa]) | ((u32)f2bf(s[5][aa]) << 16);
          w.w = (u32)f2bf(s[6][aa]) | ((u32)f2bf(s[7][aa]) << 16);
          *(uint4*)&pT[(h*200 + c*8 + aa)*8] = w;
        }
      }
    }
    __syncthreads();

    if (lane_on){
      int d0 = (t & 31) >> 1;
      int half = t & 1;
      float o[8] = {0.f,0.f,0.f,0.f,0.f,0.f,0.f,0.f};
      int cbeg = half ? 13 : 0;
      int cnum = half ? 12 : 13;
      for (int cc = 0; cc < cnum; ++cc){
        int c2 = cbeg + cc;
        uint4 vv = *(const uint4*)&VT[(h*16 + d0)*200 + c2*8];
        float vf[8]; unpack8(vv, vf);
        #pragma unroll
        for (int aa = 0; aa < 8; ++aa){
          uint4 pv = *(const uint4*)&pT[(h*200 + c2*8 + aa)*8];
          float pf[8]; unpack8(pv, pf);
          #pragma unroll
          for (int ii = 0; ii < 8; ++ii) o[ii] = fmaf(pf[ii], vf[aa], o[ii]);
        }
      }
      #pragma unroll
      for (int ii = 0; ii < 8; ++ii) o[ii] += __shfl_xor(o[ii], 1);
      if (!half){
        #pragma unroll
        for (int ii = 0; ii < 8; ++ii)
          qhg[(size_t)(b*AA + it0 + ii)*DD + colbase + h*16 + d0] = f2bf(o[ii]);
      }
    }
    __syncthreads();
  }
}

// ---------------- K4: glimpse = heads @ W_out -> proj cols [0..127] (bf16) ----------------
__global__ __launch_bounds__(256) void k_glimpse(const u16* __restrict__ qhg,
                                                 const float* __restrict__ Wo,
                                                 u16* __restrict__ proj){
  __shared__ float Ast[128][68];
  __shared__ float Bs[128][68];
  int t = threadIdx.x;
  int m0 = blockIdx.x * 64;
  int n0 = blockIdx.y * 64;
  for (int p = 0; p < 8; ++p){
    int idx = t + p*256;
    int row = idx >> 5, c4 = (idx & 31) << 2;
    ushort4 hv = *(const ushort4*)(qhg + (size_t)(m0+row)*DD + c4);
    Ast[c4+0][row] = bf2f(hv.x); Ast[c4+1][row] = bf2f(hv.y);
    Ast[c4+2][row] = bf2f(hv.z); Ast[c4+3][row] = bf2f(hv.w);
  }
  for (int p = 0; p < 8; ++p){
    int idx = t + p*256;
    int k = idx >> 4, c4 = (idx & 15) << 2;
    *(float4*)&Bs[k][c4] = *(const float4*)(Wo + (size_t)k*DD + n0 + c4);
  }
  __syncthreads();
  int tx = t & 15, ty = t >> 4;
  float acc[4][4] = {};
  for (int k = 0; k < 128; ++k){
    float4 av = *(const float4*)&Ast[k][ty*4];
    float4 bv = *(const float4*)&Bs[k][tx*4];
    float a_[4] = {av.x, av.y, av.z, av.w};
    float b_[4] = {bv.x, bv.y, bv.z, bv.w};
    #pragma unroll
    for (int r = 0; r < 4; ++r)
      #pragma unroll
      for (int cc = 0; cc < 4; ++cc) acc[r][cc] = fmaf(a_[r], b_[cc], acc[r][cc]);
  }
  #pragma unroll
  for (int r = 0; r < 4; ++r){
    int row = m0 + ty*4 + r;
    ushort4 o;
    o.x = f2bf(acc[r][0]); o.y = f2bf(acc[r][1]);
    o.z = f2bf(acc[r][2]); o.w = f2bf(acc[r][3]);
    *(ushort4*)(proj + (size_t)row*N3 + n0 + tx*4) = o;
  }
}

// ---------------- K5: logits -> tanh -> mask -> log_softmax -> gather -> sum ----------------
__global__ __launch_bounds__(256) void k_logits(const u16* __restrict__ proj,
                                                const int* __restrict__ rank,
                                                const int* __restrict__ oa,
                                                float* __restrict__ outlps){
  __shared__ __align__(16) u16 LKT[128*200];   // [d][a]
  __shared__ __align__(16) u16 gT[4*128*8];    // [g][d][ii]
  __shared__ float lps_acc;
  const int b = blockIdx.x;
  const int t = threadIdx.x;
  const float inv_sqrt_d = 0.08838834764831843f;  // 1/sqrt(128)

  for (int idx = t; idx < 200*128; idx += 256){
    int a = idx >> 7, col = idx & 127;
    LKT[col*200 + a] = proj[(size_t)(b*AA + a)*N3 + 256 + col];
  }
  const bool lane_on = (t < 128);               // 4 groups x 32 lanes compute
  const int g = t >> 5, c = t & 31;             // g in 0..3 when lane_on
  int r8i[8];
  if (lane_on && c < 25){
    #pragma unroll
    for (int aa = 0; aa < 8; ++aa) r8i[aa] = rank[b*AA + c*8 + aa];
  }
  if (t == 0) lps_acc = 0.f;
  __syncthreads();

  for (int pass = 0; pass < 7; ++pass){
    __syncthreads();
    for (int idx = t; idx < 32*128; idx += 256){
      int rl = idx >> 7, col = idx & 127;
      int gg = rl >> 3, ii = rl & 7;
      int tile = pass*4 + gg;
      if (tile < 25){
        gT[(gg*128 + col)*8 + ii] = proj[(size_t)(b*AA + tile*8 + ii)*N3 + col];
      }
    }
    __syncthreads();
    if (!lane_on) continue;
    int tile = pass*4 + g;
    if (tile >= 25) continue;

    float s[8][8];
    if (c < 25){
      #pragma unroll
      for (int ii = 0; ii < 8; ++ii)
        #pragma unroll
        for (int aa = 0; aa < 8; ++aa) s[ii][aa] = 0.f;
      for (int d0 = 0; d0 < 128; ++d0){
        uint4 lk = *(const uint4*)&LKT[d0*200 + c*8];
        uint4 gv = *(const uint4*)&gT[(g*128 + d0)*8];
        float lkf[8], gf[8];
        unpack8(lk, lkf); unpack8(gv, gf);
        #pragma unroll
        for (int ii = 0; ii < 8; ++ii)
          #pragma unroll
          for (int aa = 0; aa < 8; ++aa)
            s[ii][aa] = fmaf(gf[ii], lkf[aa], s[ii][aa]);
      }
      #pragma unroll
      for (int ii = 0; ii < 8; ++ii)
        #pragma unroll
        for (int aa = 0; aa < 8; ++aa){
          float v = tanhf(s[ii][aa] * inv_sqrt_d) * 10.0f;
          s[ii][aa] = (r8i[aa] < tile*8 + ii) ? -__builtin_inff() : v;
        }
    } else {
      #pragma unroll
      for (int ii = 0; ii < 8; ++ii)
        #pragma unroll
        for (int aa = 0; aa < 8; ++aa) s[ii][aa] = -__builtin_inff();
    }
    #pragma unroll
    for (int ii = 0; ii < 8; ++ii){
      int i = tile*8 + ii;
      float m = s[ii][0];
      #pragma unroll
      for (int aa = 1; aa < 8; ++aa) m = fmaxf(m, s[ii][aa]);
      #pragma unroll
      for (int off = 16; off >= 1; off >>= 1) m = fmaxf(m, __shfl_xor(m, off, 32));
      float sum = 0.f;
      #pragma unroll
      for (int aa = 0; aa < 8; ++aa)
        sum += (s[ii][aa] > -1e30f) ? __expf(s[ii][aa] - m) : 0.f;
      #pragma unroll
      for (int off = 16; off >= 1; off >>= 1) sum += __shfl_xor(sum, off, 32);
      float lse = m + logf(sum);
      int act = oa[b*AA + i];
      if (c == (act >> 3)){
        atomicAdd(&lps_acc, s[ii][act & 7] - lse);
      }
    }
  }
  __syncthreads();
  if (t == 0) outlps[b] = lps_acc;
}

// ---------------- launch ----------------
extern "C" void kernel_launch(void* const* d_in, const int* in_sizes, int n_in,
                              void* d_out, int out_size, void* d_ws, size_t ws_size,
                              hipStream_t stream){
  const float* E  = (const float*)d_in[0];
  const int*   oa = (const int*)d_in[1];
  const float* Wp = (const float*)d_in[2];
  const float* Wn = (const float*)d_in[3];
  const float* Wf = (const float*)d_in[4];
  const float* Ws = (const float*)d_in[5];
  const float* Wo = (const float*)d_in[6];
  float* out = (float*)d_out;

  char* ws = (char*)d_ws;
  int*   rank   = (int*)ws;                     //   819,200 B
  float* fixedc = (float*)(ws + 819200);        //   524,288 B
  u16*   proj   = (u16*)(ws + 1343488);         // 157,286,400 B  [B][A][384] bf16
  u16*   qhg    = (u16*)(ws + 158629888);       //  52,428,800 B  [B][A][128] bf16 (query->heads->)
  // total workspace: 211,058,688 B

  k_act_rank<<<dim3((BB*AA)/256), 256, 0, stream>>>(oa, out, rank);
  k_fixed<<<dim3(BB), 128, 0, stream>>>(E, Wf, fixedc);
  k_proj<<<dim3((BB*AA)/64, N3/64), 256, 0, stream>>>(E, Wn, proj);
  k_query<<<dim3((BB*AA)/64, DD/64), 256, 0, stream>>>(E, oa, Wp, Ws, fixedc, qhg);
  k_attn<<<dim3(BB, 2), 256, 0, stream>>>(proj, rank, qhg);
  k_glimpse<<<dim3((BB*AA)/64, DD/64), 256, 0, stream>>>(qhg, Wo, proj);
  k_logits<<<dim3(BB), 256, 0, stream>>>(proj, rank, oa, out + BB*AA);
}

// Round 3
// 1693.885 us; speedup vs baseline: 2.1114x; 2.1114x over previous
//
#include <hip/hip_runtime.h>
#include <cstdint>
#include <cstddef>

#define BB 1024
#define AA 200
#define DD 128
#define HH 8
#define N3 384

typedef unsigned short u16;
typedef unsigned int u32;
typedef __attribute__((ext_vector_type(8))) short bf16x8;
typedef __attribute__((ext_vector_type(4))) float f32x4;

__device__ __forceinline__ float bf2f(u16 v){ return __uint_as_float(((u32)v) << 16); }
__device__ __forceinline__ u16 f2bf(float f){
  u32 u = __float_as_uint(f);
  u32 r = u + 0x7fffu + ((u >> 16) & 1u);
  return (u16)(r >> 16);
}

// ---------------- K0: copy old_action to out (as float) + build rank ----------------
__global__ void k_act_rank(const int* __restrict__ oa, float* __restrict__ out0,
                           int* __restrict__ rank){
  int m = blockIdx.x * 256 + threadIdx.x;
  if (m >= BB*AA) return;
  int v = oa[m];
  out0[m] = (float)v;
  int b = m / AA;
  int j = m - b*AA;
  rank[b*AA + v] = j;
}

// ---------------- K1: fixed_ctx = mean_a(E[b]) @ W_fixed ----------------
__global__ void k_fixed(const float* __restrict__ E, const float* __restrict__ Wf,
                        float* __restrict__ fixedc){
  int b = blockIdx.x;
  int d = threadIdx.x;              // 128 threads
  __shared__ float ge[DD];
  const float* Eb = E + (size_t)b*AA*DD;
  float s = 0.f;
  for (int a = 0; a < AA; ++a) s += Eb[a*DD + d];
  ge[d] = s * (1.0f/AA);
  __syncthreads();
  float acc = 0.f;
  for (int k = 0; k < DD; ++k) acc = fmaf(ge[k], Wf[k*DD + d], acc);
  fixedc[b*DD + d] = acc;
}

// ---------------- K2a: proj = E @ W_node  (M=B*A, K=128, N=384) -> bf16 ----------------
__global__ __launch_bounds__(256) void k_proj(const float* __restrict__ E,
                                              const float* __restrict__ Wn,
                                              u16* __restrict__ proj){
  __shared__ float Ast[128][68];   // transposed A tile [k][row]
  __shared__ float Bs[128][68];    // [k][col]
  int t = threadIdx.x;
  int m0 = blockIdx.x * 64;
  int n0 = blockIdx.y * 64;
  for (int p = 0; p < 8; ++p){
    int idx = t + p*256;
    int row = idx >> 5, c4 = (idx & 31) << 2;
    float4 ev = *(const float4*)(E + (size_t)(m0+row)*DD + c4);
    Ast[c4+0][row] = ev.x; Ast[c4+1][row] = ev.y;
    Ast[c4+2][row] = ev.z; Ast[c4+3][row] = ev.w;
  }
  for (int p = 0; p < 8; ++p){
    int idx = t + p*256;
    int k = idx >> 4, c4 = (idx & 15) << 2;
    *(float4*)&Bs[k][c4] = *(const float4*)(Wn + (size_t)k*N3 + n0 + c4);
  }
  __syncthreads();
  int tx = t & 15, ty = t >> 4;
  float acc[4][4] = {};
  for (int k = 0; k < 128; ++k){
    float4 av = *(const float4*)&Ast[k][ty*4];
    float4 bv = *(const float4*)&Bs[k][tx*4];
    float a_[4] = {av.x, av.y, av.z, av.w};
    float b_[4] = {bv.x, bv.y, bv.z, bv.w};
    #pragma unroll
    for (int r = 0; r < 4; ++r)
      #pragma unroll
      for (int cc = 0; cc < 4; ++cc) acc[r][cc] = fmaf(a_[r], b_[cc], acc[r][cc]);
  }
  #pragma unroll
  for (int r = 0; r < 4; ++r){
    int row = m0 + ty*4 + r;
    ushort4 o;
    o.x = f2bf(acc[r][0]); o.y = f2bf(acc[r][1]);
    o.z = f2bf(acc[r][2]); o.w = f2bf(acc[r][3]);
    *(ushort4*)(proj + (size_t)row*N3 + n0 + tx*4) = o;
  }
}

// ---------------- K2b: query = fixed_ctx + gather(E,prev) @ W_step -> bf16 ----------------
__global__ __launch_bounds__(256) void k_query(const float* __restrict__ E,
                                               const int* __restrict__ oa,
                                               const float* __restrict__ Wp,
                                               const float* __restrict__ Ws,
                                               const float* __restrict__ fixedc,
                                               u16* __restrict__ qhg){
  __shared__ float Ast[128][68];
  __shared__ float Bs[128][68];
  int t = threadIdx.x;
  int m0 = blockIdx.x * 64;
  int n0 = blockIdx.y * 64;
  for (int p = 0; p < 8; ++p){
    int idx = t + p*256;
    int row = idx >> 5, c4 = (idx & 31) << 2;
    int m = m0 + row;
    int b = m / AA, i = m - b*AA;
    const float* src = (i == 0) ? Wp : (E + (size_t)(b*AA + oa[b*AA + i - 1])*DD);
    float4 ev = *(const float4*)(src + c4);
    Ast[c4+0][row] = ev.x; Ast[c4+1][row] = ev.y;
    Ast[c4+2][row] = ev.z; Ast[c4+3][row] = ev.w;
  }
  for (int p = 0; p < 8; ++p){
    int idx = t + p*256;
    int k = idx >> 4, c4 = (idx & 15) << 2;
    *(float4*)&Bs[k][c4] = *(const float4*)(Ws + (size_t)k*DD + n0 + c4);
  }
  __syncthreads();
  int tx = t & 15, ty = t >> 4;
  float acc[4][4] = {};
  for (int k = 0; k < 128; ++k){
    float4 av = *(const float4*)&Ast[k][ty*4];
    float4 bv = *(const float4*)&Bs[k][tx*4];
    float a_[4] = {av.x, av.y, av.z, av.w};
    float b_[4] = {bv.x, bv.y, bv.z, bv.w};
    #pragma unroll
    for (int r = 0; r < 4; ++r)
      #pragma unroll
      for (int cc = 0; cc < 4; ++cc) acc[r][cc] = fmaf(a_[r], b_[cc], acc[r][cc]);
  }
  #pragma unroll
  for (int r = 0; r < 4; ++r){
    int row = m0 + ty*4 + r;
    int b = row / AA;
    ushort4 o;
    o.x = f2bf(acc[r][0] + fixedc[b*DD + n0 + tx*4 + 0]);
    o.y = f2bf(acc[r][1] + fixedc[b*DD + n0 + tx*4 + 1]);
    o.z = f2bf(acc[r][2] + fixedc[b*DD + n0 + tx*4 + 2]);
    o.w = f2bf(acc[r][3] + fixedc[b*DD + n0 + tx*4 + 3]);
    *(ushort4*)(qhg + (size_t)row*DD + n0 + tx*4) = o;
  }
}

// ---------------- K3: MFMA attention, one wave per (b, head) ----------------
// S = Q K^T / 4 (dh=16 zero-padded to K=32), mask by rank<i, softmax over a,
// P -> LDS (C-layout -> A-layout transform), H = P V via MFMA, write to qhg.
#define VSTR 232   // u16 stride: 116 dwords, gcd(116,32)=4 -> <=2-way conflicts on b128
__global__ __launch_bounds__(64) void k_attn(const u16* __restrict__ proj,
                                             const int* __restrict__ rank,
                                             u16* __restrict__ qhg){
  __shared__ __align__(16) u16 VT[16*VSTR];   // [d][a], cols>=200 zero
  __shared__ __align__(16) u16 P [16*VSTR];   // [i_loc][a], cols>=208 zero
  const int b = blockIdx.x;
  const int h = blockIdx.y;
  const int L = threadIdx.x;       // 0..63
  const int l16 = L & 15, lq = L >> 4;

  for (int idx = L; idx < 16*VSTR; idx += 64){ VT[idx] = 0; P[idx] = 0; }
  __syncthreads();

  // stage V transposed: V[a][d] = proj[(b*200+a)*384 + 128 + h*16 + d]
  for (int a = L; a < AA; a += 64){
    const u16* src = proj + ((size_t)(b*AA + a))*N3 + 128 + h*16;
    u16 d16[16];
    *(uint4*)(d16)   = *(const uint4*)(src);
    *(uint4*)(d16+8) = *(const uint4*)(src+8);
    #pragma unroll
    for (int d = 0; d < 16; ++d) VT[d*VSTR + a] = d16[d];
  }

  int ra[13];
  #pragma unroll
  for (int at = 0; at < 13; ++at){
    int a = at*16 + l16;
    ra[at] = (a < AA) ? rank[b*AA + a] : -1;   // -1 => always masked
  }
  __syncthreads();

  const u16* Kbase = proj + (size_t)b*AA*N3 + h*16;   // gK slice, row stride 384
  u16* Qbase = qhg + (size_t)b*AA*DD + h*16;          // query slice, row stride 128

  const bf16x8 zf = {0,0,0,0,0,0,0,0};
  for (int it = 0; it < 13; ++it){
    // ---- A-frag: Q[i=it*16+l16][d=lq*8+j] (zero-padded d>=16, i>=200)
    bf16x8 qf = zf;
    int qi = it*16 + l16;
    if (lq < 2 && qi < AA){
      union { uint4 u; bf16x8 v; } tmp;
      tmp.u = *(const uint4*)(Qbase + (size_t)qi*DD + lq*8);
      qf = tmp.v;
    }
    // ---- S tiles: 13 x (16x16), C-layout: row=lq*4+r, col=l16
    f32x4 S[13];
    #pragma unroll
    for (int at = 0; at < 13; ++at){
      bf16x8 kf = zf;
      int ka = at*16 + l16;
      if (lq < 2 && ka < AA){
        union { uint4 u; bf16x8 v; } tmp;
        tmp.u = *(const uint4*)(Kbase + (size_t)ka*N3 + lq*8);
        kf = tmp.v;
      }
      f32x4 z = {0.f,0.f,0.f,0.f};
      S[at] = __builtin_amdgcn_mfma_f32_16x16x32_bf16(qf, kf, z, 0, 0, 0);
    }
    // ---- scale + mask
    #pragma unroll
    for (int at = 0; at < 13; ++at)
      #pragma unroll
      for (int r = 0; r < 4; ++r){
        int i = it*16 + lq*4 + r;
        float v = S[at][r] * 0.25f;      // 1/sqrt(16)
        S[at][r] = (ra[at] < i) ? -__builtin_inff() : v;
      }
    // ---- softmax over a (13 tiles x 16 lanes within row group)
    #pragma unroll
    for (int r = 0; r < 4; ++r){
      float m = S[0][r];
      #pragma unroll
      for (int at = 1; at < 13; ++at) m = fmaxf(m, S[at][r]);
      #pragma unroll
      for (int off = 1; off < 16; off <<= 1) m = fmaxf(m, __shfl_xor(m, off));
      float sum = 0.f;
      #pragma unroll
      for (int at = 0; at < 13; ++at){
        float e = __expf(S[at][r] - m);
        S[at][r] = e; sum += e;
      }
      #pragma unroll
      for (int off = 1; off < 16; off <<= 1) sum += __shfl_xor(sum, off);
      float inv = 1.0f / sum;
      #pragma unroll
      for (int at = 0; at < 13; ++at) S[at][r] *= inv;
    }
    // ---- P -> LDS in [i_loc][a] (A-operand source)
    #pragma unroll
    for (int at = 0; at < 13; ++at)
      #pragma unroll
      for (int r = 0; r < 4; ++r)
        P[(lq*4 + r)*VSTR + at*16 + l16] = f2bf(S[at][r]);
    __syncthreads();
    // ---- H = P V : A[m=l16][k=lq*8+j+kb*32], B=VT[n=l16][k...]
    f32x4 acc = {0.f,0.f,0.f,0.f};
    #pragma unroll
    for (int kb = 0; kb < 7; ++kb){
      union { uint4 u; bf16x8 v; } pa, vb;
      pa.u = *(const uint4*)&P [l16*VSTR + kb*32 + lq*8];
      vb.u = *(const uint4*)&VT[l16*VSTR + kb*32 + lq*8];
      acc = __builtin_amdgcn_mfma_f32_16x16x32_bf16(pa.v, vb.v, acc, 0, 0, 0);
    }
    // ---- store H (C-layout): row=lq*4+r, col=l16
    #pragma unroll
    for (int r = 0; r < 4; ++r){
      int i = it*16 + lq*4 + r;
      if (i < AA) Qbase[(size_t)i*DD + l16] = f2bf(acc[r]);
    }
    __syncthreads();
  }
}

// ---------------- K4: glimpse = heads @ W_out -> proj cols [0..127] (bf16) ----------------
__global__ __launch_bounds__(256) void k_glimpse(const u16* __restrict__ qhg,
                                                 const float* __restrict__ Wo,
                                                 u16* __restrict__ proj){
  __shared__ float Ast[128][68];
  __shared__ float Bs[128][68];
  int t = threadIdx.x;
  int m0 = blockIdx.x * 64;
  int n0 = blockIdx.y * 64;
  for (int p = 0; p < 8; ++p){
    int idx = t + p*256;
    int row = idx >> 5, c4 = (idx & 31) << 2;
    ushort4 hv = *(const ushort4*)(qhg + (size_t)(m0+row)*DD + c4);
    Ast[c4+0][row] = bf2f(hv.x); Ast[c4+1][row] = bf2f(hv.y);
    Ast[c4+2][row] = bf2f(hv.z); Ast[c4+3][row] = bf2f(hv.w);
  }
  for (int p = 0; p < 8; ++p){
    int idx = t + p*256;
    int k = idx >> 4, c4 = (idx & 15) << 2;
    *(float4*)&Bs[k][c4] = *(const float4*)(Wo + (size_t)k*DD + n0 + c4);
  }
  __syncthreads();
  int tx = t & 15, ty = t >> 4;
  float acc[4][4] = {};
  for (int k = 0; k < 128; ++k){
    float4 av = *(const float4*)&Ast[k][ty*4];
    float4 bv = *(const float4*)&Bs[k][tx*4];
    float a_[4] = {av.x, av.y, av.z, av.w};
    float b_[4] = {bv.x, bv.y, bv.z, bv.w};
    #pragma unroll
    for (int r = 0; r < 4; ++r)
      #pragma unroll
      for (int cc = 0; cc < 4; ++cc) acc[r][cc] = fmaf(a_[r], b_[cc], acc[r][cc]);
  }
  #pragma unroll
  for (int r = 0; r < 4; ++r){
    int row = m0 + ty*4 + r;
    ushort4 o;
    o.x = f2bf(acc[r][0]); o.y = f2bf(acc[r][1]);
    o.z = f2bf(acc[r][2]); o.w = f2bf(acc[r][3]);
    *(ushort4*)(proj + (size_t)row*N3 + n0 + tx*4) = o;
  }
}

// ---------------- K5: logits -> tanh -> mask -> log_softmax -> gather -> sum ----------------
__device__ __forceinline__ void unpack8(uint4 v, float* f){
  f[0] = __uint_as_float(v.x << 16); f[1] = __uint_as_float(v.x & 0xffff0000u);
  f[2] = __uint_as_float(v.y << 16); f[3] = __uint_as_float(v.y & 0xffff0000u);
  f[4] = __uint_as_float(v.z << 16); f[5] = __uint_as_float(v.z & 0xffff0000u);
  f[6] = __uint_as_float(v.w << 16); f[7] = __uint_as_float(v.w & 0xffff0000u);
}

__global__ __launch_bounds__(256) void k_logits(const u16* __restrict__ proj,
                                                const int* __restrict__ rank,
                                                const int* __restrict__ oa,
                                                float* __restrict__ outlps){
  __shared__ __align__(16) u16 LKT[128*200];   // [d][a]
  __shared__ __align__(16) u16 gT[4*128*8];    // [g][d][ii]
  __shared__ float lps_acc;
  const int b = blockIdx.x;
  const int t = threadIdx.x;
  const float inv_sqrt_d = 0.08838834764831843f;  // 1/sqrt(128)

  for (int idx = t; idx < 200*128; idx += 256){
    int a = idx >> 7, col = idx & 127;
    LKT[col*200 + a] = proj[(size_t)(b*AA + a)*N3 + 256 + col];
  }
  const bool lane_on = (t < 128);               // 4 groups x 32 lanes compute
  const int g = t >> 5, c = t & 31;             // g in 0..3 when lane_on
  int r8i[8];
  if (lane_on && c < 25){
    #pragma unroll
    for (int aa = 0; aa < 8; ++aa) r8i[aa] = rank[b*AA + c*8 + aa];
  }
  if (t == 0) lps_acc = 0.f;
  __syncthreads();

  for (int pass = 0; pass < 7; ++pass){
    __syncthreads();
    for (int idx = t; idx < 32*128; idx += 256){
      int rl = idx >> 7, col = idx & 127;
      int gg = rl >> 3, ii = rl & 7;
      int tile = pass*4 + gg;
      if (tile < 25){
        gT[(gg*128 + col)*8 + ii] = proj[(size_t)(b*AA + tile*8 + ii)*N3 + col];
      }
    }
    __syncthreads();
    if (!lane_on) continue;
    int tile = pass*4 + g;
    if (tile >= 25) continue;

    float s[8][8];
    if (c < 25){
      #pragma unroll
      for (int ii = 0; ii < 8; ++ii)
        #pragma unroll
        for (int aa = 0; aa < 8; ++aa) s[ii][aa] = 0.f;
      for (int d0 = 0; d0 < 128; ++d0){
        uint4 lk = *(const uint4*)&LKT[d0*200 + c*8];
        uint4 gv = *(const uint4*)&gT[(g*128 + d0)*8];
        float lkf[8], gf[8];
        unpack8(lk, lkf); unpack8(gv, gf);
        #pragma unroll
        for (int ii = 0; ii < 8; ++ii)
          #pragma unroll
          for (int aa = 0; aa < 8; ++aa)
            s[ii][aa] = fmaf(gf[ii], lkf[aa], s[ii][aa]);
      }
      #pragma unroll
      for (int ii = 0; ii < 8; ++ii)
        #pragma unroll
        for (int aa = 0; aa < 8; ++aa){
          float v = tanhf(s[ii][aa] * inv_sqrt_d) * 10.0f;
          s[ii][aa] = (r8i[aa] < tile*8 + ii) ? -__builtin_inff() : v;
        }
    } else {
      #pragma unroll
      for (int ii = 0; ii < 8; ++ii)
        #pragma unroll
        for (int aa = 0; aa < 8; ++aa) s[ii][aa] = -__builtin_inff();
    }
    #pragma unroll
    for (int ii = 0; ii < 8; ++ii){
      int i = tile*8 + ii;
      float m = s[ii][0];
      #pragma unroll
      for (int aa = 1; aa < 8; ++aa) m = fmaxf(m, s[ii][aa]);
      #pragma unroll
      for (int off = 16; off >= 1; off >>= 1) m = fmaxf(m, __shfl_xor(m, off, 32));
      float sum = 0.f;
      #pragma unroll
      for (int aa = 0; aa < 8; ++aa)
        sum += (s[ii][aa] > -1e30f) ? __expf(s[ii][aa] - m) : 0.f;
      #pragma unroll
      for (int off = 16; off >= 1; off >>= 1) sum += __shfl_xor(sum, off, 32);
      float lse = m + logf(sum);
      int act = oa[b*AA + i];
      if (c == (act >> 3)){
        atomicAdd(&lps_acc, s[ii][act & 7] - lse);
      }
    }
  }
  __syncthreads();
  if (t == 0) outlps[b] = lps_acc;
}

// ---------------- launch ----------------
extern "C" void kernel_launch(void* const* d_in, const int* in_sizes, int n_in,
                              void* d_out, int out_size, void* d_ws, size_t ws_size,
                              hipStream_t stream){
  const float* E  = (const float*)d_in[0];
  const int*   oa = (const int*)d_in[1];
  const float* Wp = (const float*)d_in[2];
  const float* Wn = (const float*)d_in[3];
  const float* Wf = (const float*)d_in[4];
  const float* Ws = (const float*)d_in[5];
  const float* Wo = (const float*)d_in[6];
  float* out = (float*)d_out;

  char* ws = (char*)d_ws;
  int*   rank   = (int*)ws;                     //   819,200 B
  float* fixedc = (float*)(ws + 819200);        //   524,288 B
  u16*   proj   = (u16*)(ws + 1343488);         // 157,286,400 B  [B][A][384] bf16
  u16*   qhg    = (u16*)(ws + 158629888);       //  52,428,800 B  [B][A][128] bf16 (query->heads->)
  // total workspace: 211,058,688 B

  k_act_rank<<<dim3((BB*AA)/256), 256, 0, stream>>>(oa, out, rank);
  k_fixed<<<dim3(BB), 128, 0, stream>>>(E, Wf, fixedc);
  k_proj<<<dim3((BB*AA)/64, N3/64), 256, 0, stream>>>(E, Wn, proj);
  k_query<<<dim3((BB*AA)/64, DD/64), 256, 0, stream>>>(E, oa, Wp, Ws, fixedc, qhg);
  k_attn<<<dim3(BB, HH), 64, 0, stream>>>(proj, rank, qhg);
  k_glimpse<<<dim3((BB*AA)/64, DD/64), 256, 0, stream>>>(qhg, Wo, proj);
  k_logits<<<dim3(BB), 256, 0, stream>>>(proj, rank, oa, out + BB*AA);
}

// Round 4
// 1260.388 us; speedup vs baseline: 2.8376x; 1.3439x over previous
//
#include <hip/hip_runtime.h>
#include <cstdint>
#include <cstddef>

#define BB 1024
#define AA 200
#define DD 128
#define HH 8
#define N3 384

typedef unsigned short u16;
typedef unsigned int u32;
typedef __attribute__((ext_vector_type(8))) short bf16x8;
typedef __attribute__((ext_vector_type(4))) float f32x4;

__device__ __forceinline__ float bf2f(u16 v){ return __uint_as_float(((u32)v) << 16); }
__device__ __forceinline__ u16 f2bf(float f){
  u32 u = __float_as_uint(f);
  u32 r = u + 0x7fffu + ((u >> 16) & 1u);
  return (u16)(r >> 16);
}

// ---------------- K0: copy old_action to out (as float) + build rank ----------------
__global__ void k_act_rank(const int* __restrict__ oa, float* __restrict__ out0,
                           int* __restrict__ rank){
  int m = blockIdx.x * 256 + threadIdx.x;
  if (m >= BB*AA) return;
  int v = oa[m];
  out0[m] = (float)v;
  int b = m / AA;
  int j = m - b*AA;
  rank[b*AA + v] = j;
}

// ---------------- K1: fixed_ctx = mean_a(E[b]) @ W_fixed ----------------
__global__ void k_fixed(const float* __restrict__ E, const float* __restrict__ Wf,
                        float* __restrict__ fixedc){
  int b = blockIdx.x;
  int d = threadIdx.x;              // 128 threads
  __shared__ float ge[DD];
  const float* Eb = E + (size_t)b*AA*DD;
  float s = 0.f;
  for (int a = 0; a < AA; ++a) s += Eb[a*DD + d];
  ge[d] = s * (1.0f/AA);
  __syncthreads();
  float acc = 0.f;
  for (int k = 0; k < DD; ++k) acc = fmaf(ge[k], Wf[k*DD + d], acc);
  fixedc[b*DD + d] = acc;
}

// ---------------- K2a: proj = E @ W_node  (M=B*A, K=128, N=384) -> bf16 ----------------
__global__ __launch_bounds__(256) void k_proj(const float* __restrict__ E,
                                              const float* __restrict__ Wn,
                                              u16* __restrict__ proj){
  __shared__ float Ast[128][68];   // transposed A tile [k][row]
  __shared__ float Bs[128][68];    // [k][col]
  int t = threadIdx.x;
  int m0 = blockIdx.x * 64;
  int n0 = blockIdx.y * 64;
  for (int p = 0; p < 8; ++p){
    int idx = t + p*256;
    int row = idx >> 5, c4 = (idx & 31) << 2;
    float4 ev = *(const float4*)(E + (size_t)(m0+row)*DD + c4);
    Ast[c4+0][row] = ev.x; Ast[c4+1][row] = ev.y;
    Ast[c4+2][row] = ev.z; Ast[c4+3][row] = ev.w;
  }
  for (int p = 0; p < 8; ++p){
    int idx = t + p*256;
    int k = idx >> 4, c4 = (idx & 15) << 2;
    *(float4*)&Bs[k][c4] = *(const float4*)(Wn + (size_t)k*N3 + n0 + c4);
  }
  __syncthreads();
  int tx = t & 15, ty = t >> 4;
  float acc[4][4] = {};
  for (int k = 0; k < 128; ++k){
    float4 av = *(const float4*)&Ast[k][ty*4];
    float4 bv = *(const float4*)&Bs[k][tx*4];
    float a_[4] = {av.x, av.y, av.z, av.w};
    float b_[4] = {bv.x, bv.y, bv.z, bv.w};
    #pragma unroll
    for (int r = 0; r < 4; ++r)
      #pragma unroll
      for (int cc = 0; cc < 4; ++cc) acc[r][cc] = fmaf(a_[r], b_[cc], acc[r][cc]);
  }
  #pragma unroll
  for (int r = 0; r < 4; ++r){
    int row = m0 + ty*4 + r;
    ushort4 o;
    o.x = f2bf(acc[r][0]); o.y = f2bf(acc[r][1]);
    o.z = f2bf(acc[r][2]); o.w = f2bf(acc[r][3]);
    *(ushort4*)(proj + (size_t)row*N3 + n0 + tx*4) = o;
  }
}

// ---------------- K2b: query = fixed_ctx + gather(E,prev) @ W_step -> bf16 ----------------
__global__ __launch_bounds__(256) void k_query(const float* __restrict__ E,
                                               const int* __restrict__ oa,
                                               const float* __restrict__ Wp,
                                               const float* __restrict__ Ws,
                                               const float* __restrict__ fixedc,
                                               u16* __restrict__ qhg){
  __shared__ float Ast[128][68];
  __shared__ float Bs[128][68];
  int t = threadIdx.x;
  int m0 = blockIdx.x * 64;
  int n0 = blockIdx.y * 64;
  for (int p = 0; p < 8; ++p){
    int idx = t + p*256;
    int row = idx >> 5, c4 = (idx & 31) << 2;
    int m = m0 + row;
    int b = m / AA, i = m - b*AA;
    const float* src = (i == 0) ? Wp : (E + (size_t)(b*AA + oa[b*AA + i - 1])*DD);
    float4 ev = *(const float4*)(src + c4);
    Ast[c4+0][row] = ev.x; Ast[c4+1][row] = ev.y;
    Ast[c4+2][row] = ev.z; Ast[c4+3][row] = ev.w;
  }
  for (int p = 0; p < 8; ++p){
    int idx = t + p*256;
    int k = idx >> 4, c4 = (idx & 15) << 2;
    *(float4*)&Bs[k][c4] = *(const float4*)(Ws + (size_t)k*DD + n0 + c4);
  }
  __syncthreads();
  int tx = t & 15, ty = t >> 4;
  float acc[4][4] = {};
  for (int k = 0; k < 128; ++k){
    float4 av = *(const float4*)&Ast[k][ty*4];
    float4 bv = *(const float4*)&Bs[k][tx*4];
    float a_[4] = {av.x, av.y, av.z, av.w};
    float b_[4] = {bv.x, bv.y, bv.z, bv.w};
    #pragma unroll
    for (int r = 0; r < 4; ++r)
      #pragma unroll
      for (int cc = 0; cc < 4; ++cc) acc[r][cc] = fmaf(a_[r], b_[cc], acc[r][cc]);
  }
  #pragma unroll
  for (int r = 0; r < 4; ++r){
    int row = m0 + ty*4 + r;
    int b = row / AA;
    ushort4 o;
    o.x = f2bf(acc[r][0] + fixedc[b*DD + n0 + tx*4 + 0]);
    o.y = f2bf(acc[r][1] + fixedc[b*DD + n0 + tx*4 + 1]);
    o.z = f2bf(acc[r][2] + fixedc[b*DD + n0 + tx*4 + 2]);
    o.w = f2bf(acc[r][3] + fixedc[b*DD + n0 + tx*4 + 3]);
    *(ushort4*)(qhg + (size_t)row*DD + n0 + tx*4) = o;
  }
}

// ---------------- K3: MFMA attention, one wave per (b, head) ----------------
#define VSTR 232   // u16 stride
__global__ __launch_bounds__(64) void k_attn(const u16* __restrict__ proj,
                                             const int* __restrict__ rank,
                                             u16* __restrict__ qhg){
  __shared__ __align__(16) u16 VT[16*VSTR];   // [d][a], cols>=200 zero
  __shared__ __align__(16) u16 P [16*VSTR];   // [i_loc][a], cols>=208 zero
  const int b = blockIdx.x;
  const int h = blockIdx.y;
  const int L = threadIdx.x;       // 0..63
  const int l16 = L & 15, lq = L >> 4;

  for (int idx = L; idx < 16*VSTR; idx += 64){ VT[idx] = 0; P[idx] = 0; }
  __syncthreads();

  for (int a = L; a < AA; a += 64){
    const u16* src = proj + ((size_t)(b*AA + a))*N3 + 128 + h*16;
    u16 d16[16];
    *(uint4*)(d16)   = *(const uint4*)(src);
    *(uint4*)(d16+8) = *(const uint4*)(src+8);
    #pragma unroll
    for (int d = 0; d < 16; ++d) VT[d*VSTR + a] = d16[d];
  }

  int ra[13];
  #pragma unroll
  for (int at = 0; at < 13; ++at){
    int a = at*16 + l16;
    ra[at] = (a < AA) ? rank[b*AA + a] : -1;
  }
  __syncthreads();

  const u16* Kbase = proj + (size_t)b*AA*N3 + h*16;
  u16* Qbase = qhg + (size_t)b*AA*DD + h*16;

  const bf16x8 zf = {0,0,0,0,0,0,0,0};
  for (int it = 0; it < 13; ++it){
    bf16x8 qf = zf;
    int qi = it*16 + l16;
    if (lq < 2 && qi < AA){
      union { uint4 u; bf16x8 v; } tmp;
      tmp.u = *(const uint4*)(Qbase + (size_t)qi*DD + lq*8);
      qf = tmp.v;
    }
    f32x4 S[13];
    #pragma unroll
    for (int at = 0; at < 13; ++at){
      bf16x8 kf = zf;
      int ka = at*16 + l16;
      if (lq < 2 && ka < AA){
        union { uint4 u; bf16x8 v; } tmp;
        tmp.u = *(const uint4*)(Kbase + (size_t)ka*N3 + lq*8);
        kf = tmp.v;
      }
      f32x4 z = {0.f,0.f,0.f,0.f};
      S[at] = __builtin_amdgcn_mfma_f32_16x16x32_bf16(qf, kf, z, 0, 0, 0);
    }
    #pragma unroll
    for (int at = 0; at < 13; ++at)
      #pragma unroll
      for (int r = 0; r < 4; ++r){
        int i = it*16 + lq*4 + r;
        float v = S[at][r] * 0.25f;
        S[at][r] = (ra[at] < i) ? -__builtin_inff() : v;
      }
    #pragma unroll
    for (int r = 0; r < 4; ++r){
      float m = S[0][r];
      #pragma unroll
      for (int at = 1; at < 13; ++at) m = fmaxf(m, S[at][r]);
      #pragma unroll
      for (int off = 1; off < 16; off <<= 1) m = fmaxf(m, __shfl_xor(m, off));
      float sum = 0.f;
      #pragma unroll
      for (int at = 0; at < 13; ++at){
        float e = __expf(S[at][r] - m);
        S[at][r] = e; sum += e;
      }
      #pragma unroll
      for (int off = 1; off < 16; off <<= 1) sum += __shfl_xor(sum, off);
      float inv = 1.0f / sum;
      #pragma unroll
      for (int at = 0; at < 13; ++at) S[at][r] *= inv;
    }
    #pragma unroll
    for (int at = 0; at < 13; ++at)
      #pragma unroll
      for (int r = 0; r < 4; ++r)
        P[(lq*4 + r)*VSTR + at*16 + l16] = f2bf(S[at][r]);
    __syncthreads();
    f32x4 acc = {0.f,0.f,0.f,0.f};
    #pragma unroll
    for (int kb = 0; kb < 7; ++kb){
      union { uint4 u; bf16x8 v; } pa, vb;
      pa.u = *(const uint4*)&P [l16*VSTR + kb*32 + lq*8];
      vb.u = *(const uint4*)&VT[l16*VSTR + kb*32 + lq*8];
      acc = __builtin_amdgcn_mfma_f32_16x16x32_bf16(pa.v, vb.v, acc, 0, 0, 0);
    }
    #pragma unroll
    for (int r = 0; r < 4; ++r){
      int i = it*16 + lq*4 + r;
      if (i < AA) Qbase[(size_t)i*DD + l16] = f2bf(acc[r]);
    }
    __syncthreads();
  }
}

// ---------------- K4: glimpse = heads @ W_out -> proj cols [0..127] (bf16) ----------------
__global__ __launch_bounds__(256) void k_glimpse(const u16* __restrict__ qhg,
                                                 const float* __restrict__ Wo,
                                                 u16* __restrict__ proj){
  __shared__ float Ast[128][68];
  __shared__ float Bs[128][68];
  int t = threadIdx.x;
  int m0 = blockIdx.x * 64;
  int n0 = blockIdx.y * 64;
  for (int p = 0; p < 8; ++p){
    int idx = t + p*256;
    int row = idx >> 5, c4 = (idx & 31) << 2;
    ushort4 hv = *(const ushort4*)(qhg + (size_t)(m0+row)*DD + c4);
    Ast[c4+0][row] = bf2f(hv.x); Ast[c4+1][row] = bf2f(hv.y);
    Ast[c4+2][row] = bf2f(hv.z); Ast[c4+3][row] = bf2f(hv.w);
  }
  for (int p = 0; p < 8; ++p){
    int idx = t + p*256;
    int k = idx >> 4, c4 = (idx & 15) << 2;
    *(float4*)&Bs[k][c4] = *(const float4*)(Wo + (size_t)k*DD + n0 + c4);
  }
  __syncthreads();
  int tx = t & 15, ty = t >> 4;
  float acc[4][4] = {};
  for (int k = 0; k < 128; ++k){
    float4 av = *(const float4*)&Ast[k][ty*4];
    float4 bv = *(const float4*)&Bs[k][tx*4];
    float a_[4] = {av.x, av.y, av.z, av.w};
    float b_[4] = {bv.x, bv.y, bv.z, bv.w};
    #pragma unroll
    for (int r = 0; r < 4; ++r)
      #pragma unroll
      for (int cc = 0; cc < 4; ++cc) acc[r][cc] = fmaf(a_[r], b_[cc], acc[r][cc]);
  }
  #pragma unroll
  for (int r = 0; r < 4; ++r){
    int row = m0 + ty*4 + r;
    ushort4 o;
    o.x = f2bf(acc[r][0]); o.y = f2bf(acc[r][1]);
    o.z = f2bf(acc[r][2]); o.w = f2bf(acc[r][3]);
    *(ushort4*)(proj + (size_t)row*N3 + n0 + tx*4) = o;
  }
}

// ---------------- K5: MFMA logits: tanh -> mask -> log_softmax -> gather -> sum ----------------
// Per block b: S[i][a] = glimpse[i] . logit_K[a] over K=128 via 16x16x32 MFMA.
// 4 waves split 13 i-tiles; A/B frags loaded directly from global (L1/L2-resident).
__global__ __launch_bounds__(256) void k_logits(const u16* __restrict__ proj,
                                                const int* __restrict__ rank,
                                                const int* __restrict__ oa,
                                                float* __restrict__ outlps){
  __shared__ float red[4];
  const int b = blockIdx.x;
  const int t = threadIdx.x;
  const int w = t >> 6, L = t & 63;
  const int l16 = L & 15, lq = L >> 4;
  const float inv_sqrt_d = 0.08838834764831843f;  // 1/sqrt(128)

  const u16* Gbase  = proj + (size_t)b*AA*N3;       // glimpse cols [0..127]
  const u16* LKbase = Gbase + 256;                  // logit_K cols [256..383]

  int ra[13];
  #pragma unroll
  for (int at = 0; at < 13; ++at){
    int a = at*16 + l16;
    ra[at] = (a < AA) ? rank[b*AA + a] : -1;        // -1 => always masked
  }

  float lp_part = 0.f;

  for (int it = w; it < 13; it += 4){
    // A-frags: glimpse[i = it*16 + l16][k = kb*32 + lq*8 + j]
    bf16x8 af[4];
    {
      const u16* arow = Gbase + (size_t)(it*16 + l16)*N3;
      #pragma unroll
      for (int kb = 0; kb < 4; ++kb){
        union { uint4 u; bf16x8 v; } tmp;
        tmp.u = *(const uint4*)(arow + kb*32 + lq*8);
        af[kb] = tmp.v;
      }
    }
    // S tiles: C-layout row = lq*4+r (i), col = l16 (a)
    f32x4 S[13];
    #pragma unroll
    for (int at = 0; at < 13; ++at){
      const u16* brow = LKbase + (size_t)(at*16 + l16)*N3;
      f32x4 acc = {0.f,0.f,0.f,0.f};
      #pragma unroll
      for (int kb = 0; kb < 4; ++kb){
        union { uint4 u; bf16x8 v; } tmp;
        tmp.u = *(const uint4*)(brow + kb*32 + lq*8);
        acc = __builtin_amdgcn_mfma_f32_16x16x32_bf16(af[kb], tmp.v, acc, 0, 0, 0);
      }
      S[at] = acc;
    }
    // tanh*10 + mask  (tanh = 1 - 2/(e^{2x}+1): stable at +-inf)
    #pragma unroll
    for (int at = 0; at < 13; ++at)
      #pragma unroll
      for (int r = 0; r < 4; ++r){
        int i = it*16 + lq*4 + r;
        float x = S[at][r] * inv_sqrt_d;
        float e = __expf(2.0f*x);
        float th = 1.0f - 2.0f/(e + 1.0f);
        S[at][r] = (ra[at] < i) ? -__builtin_inff() : 10.0f*th;
      }
    // per-row logsumexp + gather of selected action
    #pragma unroll
    for (int r = 0; r < 4; ++r){
      int i = it*16 + lq*4 + r;
      float m = S[0][r];
      #pragma unroll
      for (int at = 1; at < 13; ++at) m = fmaxf(m, S[at][r]);
      #pragma unroll
      for (int off = 1; off < 16; off <<= 1) m = fmaxf(m, __shfl_xor(m, off));
      float sum = 0.f;
      #pragma unroll
      for (int at = 0; at < 13; ++at) sum += __expf(S[at][r] - m);
      #pragma unroll
      for (int off = 1; off < 16; off <<= 1) sum += __shfl_xor(sum, off);
      if (i < AA){
        float lse = m + __logf(sum);
        int act = oa[b*AA + i];                     // broadcast within row group
        if ((act & 15) == l16){
          int at0 = act >> 4;
          #pragma unroll
          for (int at = 0; at < 13; ++at)
            if (at == at0) lp_part += S[at][r] - lse;
        }
      }
    }
  }
  // reduce: wave, then block
  #pragma unroll
  for (int off = 1; off < 64; off <<= 1) lp_part += __shfl_xor(lp_part, off);
  if (L == 0) red[w] = lp_part;
  __syncthreads();
  if (t == 0) outlps[b] = red[0] + red[1] + red[2] + red[3];
}

// ---------------- launch ----------------
extern "C" void kernel_launch(void* const* d_in, const int* in_sizes, int n_in,
                              void* d_out, int out_size, void* d_ws, size_t ws_size,
                              hipStream_t stream){
  const float* E  = (const float*)d_in[0];
  const int*   oa = (const int*)d_in[1];
  const float* Wp = (const float*)d_in[2];
  const float* Wn = (const float*)d_in[3];
  const float* Wf = (const float*)d_in[4];
  const float* Ws = (const float*)d_in[5];
  const float* Wo = (const float*)d_in[6];
  float* out = (float*)d_out;

  char* ws = (char*)d_ws;
  int*   rank   = (int*)ws;                     //   819,200 B
  float* fixedc = (float*)(ws + 819200);        //   524,288 B
  u16*   proj   = (u16*)(ws + 1343488);         // 157,286,400 B  [B][A][384] bf16
  u16*   qhg    = (u16*)(ws + 158629888);       //  52,428,800 B  [B][A][128] bf16
  // total workspace: 211,058,688 B

  k_act_rank<<<dim3((BB*AA)/256), 256, 0, stream>>>(oa, out, rank);
  k_fixed<<<dim3(BB), 128, 0, stream>>>(E, Wf, fixedc);
  k_proj<<<dim3((BB*AA)/64, N3/64), 256, 0, stream>>>(E, Wn, proj);
  k_query<<<dim3((BB*AA)/64, DD/64), 256, 0, stream>>>(E, oa, Wp, Ws, fixedc, qhg);
  k_attn<<<dim3(BB, HH), 64, 0, stream>>>(proj, rank, qhg);
  k_glimpse<<<dim3((BB*AA)/64, DD/64), 256, 0, stream>>>(qhg, Wo, proj);
  k_logits<<<dim3(BB), 256, 0, stream>>>(proj, rank, oa, out + BB*AA);
}

// Round 5
// 902.548 us; speedup vs baseline: 3.9627x; 1.3965x over previous
//
#include <hip/hip_runtime.h>
#include <cstdint>
#include <cstddef>

#define BB 1024
#define AA 200
#define DD 128
#define HH 8
#define N3 384

typedef unsigned short u16;
typedef unsigned int u32;
typedef __attribute__((ext_vector_type(8))) short bf16x8;
typedef __attribute__((ext_vector_type(4))) float f32x4;

__device__ __forceinline__ float bf2f(u16 v){ return __uint_as_float(((u32)v) << 16); }
__device__ __forceinline__ u16 f2bf(float f){
  u32 u = __float_as_uint(f);
  u32 r = u + 0x7fffu + ((u >> 16) & 1u);
  return (u16)(r >> 16);
}
__device__ __forceinline__ bf16x8 pack8(float4 a, float4 b){
  bf16x8 o;
  o[0] = (short)f2bf(a.x); o[1] = (short)f2bf(a.y);
  o[2] = (short)f2bf(a.z); o[3] = (short)f2bf(a.w);
  o[4] = (short)f2bf(b.x); o[5] = (short)f2bf(b.y);
  o[6] = (short)f2bf(b.z); o[7] = (short)f2bf(b.w);
  return o;
}

// ---------------- K0: copy old_action to out (as float) + build rank ----------------
__global__ void k_act_rank(const int* __restrict__ oa, float* __restrict__ out0,
                           int* __restrict__ rank){
  int m = blockIdx.x * 256 + threadIdx.x;
  if (m >= BB*AA) return;
  int v = oa[m];
  out0[m] = (float)v;
  int b = m / AA;
  int j = m - b*AA;
  rank[b*AA + v] = j;
}

// ---------------- K0b: transpose+cast weights to bf16 [n][k] ----------------
__global__ void k_prep(const float* __restrict__ Wn, const float* __restrict__ Ws,
                       const float* __restrict__ Wo,
                       u16* __restrict__ WnT, u16* __restrict__ WsT,
                       u16* __restrict__ WoT){
  int idx = blockIdx.x * 256 + threadIdx.x;
  if (idx < 49152){                       // WnT: [384][128]
    int n = idx >> 7, k = idx & 127;
    WnT[idx] = f2bf(Wn[k*N3 + n]);
  } else if (idx < 65536){                // WsT: [128][128]
    int j = idx - 49152;
    int n = j >> 7, k = j & 127;
    WsT[j] = f2bf(Ws[k*DD + n]);
  } else if (idx < 81920){                // WoT: [128][128]
    int j = idx - 65536;
    int n = j >> 7, k = j & 127;
    WoT[j] = f2bf(Wo[k*DD + n]);
  }
}

// ---------------- K1: fixed_ctx = mean_a(E[b]) @ W_fixed ----------------
__global__ void k_fixed(const float* __restrict__ E, const float* __restrict__ Wf,
                        float* __restrict__ fixedc){
  int b = blockIdx.x;
  int d = threadIdx.x;              // 128 threads
  __shared__ float ge[DD];
  const float* Eb = E + (size_t)b*AA*DD;
  float s = 0.f;
  for (int a = 0; a < AA; ++a) s += Eb[a*DD + d];
  ge[d] = s * (1.0f/AA);
  __syncthreads();
  float acc = 0.f;
  for (int k = 0; k < DD; ++k) acc = fmaf(ge[k], Wf[k*DD + d], acc);
  fixedc[b*DD + d] = acc;
}

// ---------------- K2a: proj = E @ W_node via MFMA (block 128x128, wave 32x128) ----------------
__global__ __launch_bounds__(256) void k_proj_mfma(const float* __restrict__ E,
                                                   const u16* __restrict__ WnT,
                                                   u16* __restrict__ proj){
  const int t = threadIdx.x;
  const int w = t >> 6, L = t & 63;
  const int l16 = L & 15, lq = L >> 4;
  const int m0 = blockIdx.x * 128;
  const int n0 = blockIdx.y * 128;
  const int row0 = m0 + w*32;

  f32x4 acc[2][8] = {};
  const float* Arow0 = E + (size_t)(row0 + l16)*DD;
  const float* Arow1 = Arow0 + (size_t)16*DD;
  #pragma unroll
  for (int ks = 0; ks < 4; ++ks){
    int ko = ks*32 + lq*8;
    bf16x8 a0 = pack8(*(const float4*)(Arow0 + ko), *(const float4*)(Arow0 + ko + 4));
    bf16x8 a1 = pack8(*(const float4*)(Arow1 + ko), *(const float4*)(Arow1 + ko + 4));
    #pragma unroll
    for (int nt = 0; nt < 8; ++nt){
      union { uint4 u; bf16x8 v; } bb;
      bb.u = *(const uint4*)(WnT + (size_t)(n0 + nt*16 + l16)*DD + ko);
      acc[0][nt] = __builtin_amdgcn_mfma_f32_16x16x32_bf16(a0, bb.v, acc[0][nt], 0, 0, 0);
      acc[1][nt] = __builtin_amdgcn_mfma_f32_16x16x32_bf16(a1, bb.v, acc[1][nt], 0, 0, 0);
    }
  }
  #pragma unroll
  for (int mt = 0; mt < 2; ++mt)
    #pragma unroll
    for (int r = 0; r < 4; ++r){
      int row = row0 + mt*16 + lq*4 + r;
      u16* dst = proj + (size_t)row*N3 + n0;
      #pragma unroll
      for (int nt = 0; nt < 8; ++nt)
        dst[nt*16 + l16] = f2bf(acc[mt][nt][r]);
    }
}

// ---------------- K2b: query = fixed_ctx + gather(E,prev) @ W_step via MFMA ----------------
__global__ __launch_bounds__(256) void k_query_mfma(const float* __restrict__ E,
                                                    const int* __restrict__ oa,
                                                    const float* __restrict__ Wp,
                                                    const u16* __restrict__ WsT,
                                                    const float* __restrict__ fixedc,
                                                    u16* __restrict__ qhg){
  const int t = threadIdx.x;
  const int w = t >> 6, L = t & 63;
  const int l16 = L & 15, lq = L >> 4;
  const int m0 = blockIdx.x * 128;
  const int row0 = m0 + w*32;

  // gathered A rows (mt=0: row0+l16, mt=1: +16)
  const float* src[2];
  #pragma unroll
  for (int mt = 0; mt < 2; ++mt){
    int q = row0 + mt*16 + l16;
    int b = q / AA, i = q - b*AA;
    src[mt] = (i == 0) ? Wp : (E + (size_t)(b*AA + oa[b*AA + i - 1])*DD);
  }

  f32x4 acc[2][8] = {};
  #pragma unroll
  for (int ks = 0; ks < 4; ++ks){
    int ko = ks*32 + lq*8;
    bf16x8 a0 = pack8(*(const float4*)(src[0] + ko), *(const float4*)(src[0] + ko + 4));
    bf16x8 a1 = pack8(*(const float4*)(src[1] + ko), *(const float4*)(src[1] + ko + 4));
    #pragma unroll
    for (int nt = 0; nt < 8; ++nt){
      union { uint4 u; bf16x8 v; } bb;
      bb.u = *(const uint4*)(WsT + (size_t)(nt*16 + l16)*DD + ko);
      acc[0][nt] = __builtin_amdgcn_mfma_f32_16x16x32_bf16(a0, bb.v, acc[0][nt], 0, 0, 0);
      acc[1][nt] = __builtin_amdgcn_mfma_f32_16x16x32_bf16(a1, bb.v, acc[1][nt], 0, 0, 0);
    }
  }
  #pragma unroll
  for (int mt = 0; mt < 2; ++mt)
    #pragma unroll
    for (int r = 0; r < 4; ++r){
      int row = row0 + mt*16 + lq*4 + r;
      int b = row / AA;
      const float* fc = fixedc + (size_t)b*DD;
      u16* dst = qhg + (size_t)row*DD;
      #pragma unroll
      for (int nt = 0; nt < 8; ++nt)
        dst[nt*16 + l16] = f2bf(acc[mt][nt][r] + fc[nt*16 + l16]);
    }
}

// ---------------- K3: MFMA attention, one wave per (b, head) ----------------
#define VSTR 232   // u16 stride
__global__ __launch_bounds__(64) void k_attn(const u16* __restrict__ proj,
                                             const int* __restrict__ rank,
                                             u16* __restrict__ qhg){
  __shared__ __align__(16) u16 VT[16*VSTR];   // [d][a], cols>=200 zero
  __shared__ __align__(16) u16 P [16*VSTR];   // [i_loc][a], cols>=208 zero
  const int b = blockIdx.x;
  const int h = blockIdx.y;
  const int L = threadIdx.x;       // 0..63
  const int l16 = L & 15, lq = L >> 4;

  for (int idx = L; idx < 16*VSTR; idx += 64){ VT[idx] = 0; P[idx] = 0; }
  __syncthreads();

  for (int a = L; a < AA; a += 64){
    const u16* src = proj + ((size_t)(b*AA + a))*N3 + 128 + h*16;
    u16 d16[16];
    *(uint4*)(d16)   = *(const uint4*)(src);
    *(uint4*)(d16+8) = *(const uint4*)(src+8);
    #pragma unroll
    for (int d = 0; d < 16; ++d) VT[d*VSTR + a] = d16[d];
  }

  int ra[13];
  #pragma unroll
  for (int at = 0; at < 13; ++at){
    int a = at*16 + l16;
    ra[at] = (a < AA) ? rank[b*AA + a] : -1;
  }
  __syncthreads();

  const u16* Kbase = proj + (size_t)b*AA*N3 + h*16;
  u16* Qbase = qhg + (size_t)b*AA*DD + h*16;

  const bf16x8 zf = {0,0,0,0,0,0,0,0};
  for (int it = 0; it < 13; ++it){
    bf16x8 qf = zf;
    int qi = it*16 + l16;
    if (lq < 2 && qi < AA){
      union { uint4 u; bf16x8 v; } tmp;
      tmp.u = *(const uint4*)(Qbase + (size_t)qi*DD + lq*8);
      qf = tmp.v;
    }
    f32x4 S[13];
    #pragma unroll
    for (int at = 0; at < 13; ++at){
      bf16x8 kf = zf;
      int ka = at*16 + l16;
      if (lq < 2 && ka < AA){
        union { uint4 u; bf16x8 v; } tmp;
        tmp.u = *(const uint4*)(Kbase + (size_t)ka*N3 + lq*8);
        kf = tmp.v;
      }
      f32x4 z = {0.f,0.f,0.f,0.f};
      S[at] = __builtin_amdgcn_mfma_f32_16x16x32_bf16(qf, kf, z, 0, 0, 0);
    }
    #pragma unroll
    for (int at = 0; at < 13; ++at)
      #pragma unroll
      for (int r = 0; r < 4; ++r){
        int i = it*16 + lq*4 + r;
        float v = S[at][r] * 0.25f;
        S[at][r] = (ra[at] < i) ? -__builtin_inff() : v;
      }
    #pragma unroll
    for (int r = 0; r < 4; ++r){
      float m = S[0][r];
      #pragma unroll
      for (int at = 1; at < 13; ++at) m = fmaxf(m, S[at][r]);
      #pragma unroll
      for (int off = 1; off < 16; off <<= 1) m = fmaxf(m, __shfl_xor(m, off));
      float sum = 0.f;
      #pragma unroll
      for (int at = 0; at < 13; ++at){
        float e = __expf(S[at][r] - m);
        S[at][r] = e; sum += e;
      }
      #pragma unroll
      for (int off = 1; off < 16; off <<= 1) sum += __shfl_xor(sum, off);
      float inv = 1.0f / sum;
      #pragma unroll
      for (int at = 0; at < 13; ++at) S[at][r] *= inv;
    }
    #pragma unroll
    for (int at = 0; at < 13; ++at)
      #pragma unroll
      for (int r = 0; r < 4; ++r)
        P[(lq*4 + r)*VSTR + at*16 + l16] = f2bf(S[at][r]);
    __syncthreads();
    f32x4 acc = {0.f,0.f,0.f,0.f};
    #pragma unroll
    for (int kb = 0; kb < 7; ++kb){
      union { uint4 u; bf16x8 v; } pa, vb;
      pa.u = *(const uint4*)&P [l16*VSTR + kb*32 + lq*8];
      vb.u = *(const uint4*)&VT[l16*VSTR + kb*32 + lq*8];
      acc = __builtin_amdgcn_mfma_f32_16x16x32_bf16(pa.v, vb.v, acc, 0, 0, 0);
    }
    #pragma unroll
    for (int r = 0; r < 4; ++r){
      int i = it*16 + lq*4 + r;
      if (i < AA) Qbase[(size_t)i*DD + l16] = f2bf(acc[r]);
    }
    __syncthreads();
  }
}

// ---------------- K4: glimpse = heads @ W_out via MFMA -> proj cols [0..127] ----------------
__global__ __launch_bounds__(256) void k_glimpse_mfma(const u16* __restrict__ qhg,
                                                      const u16* __restrict__ WoT,
                                                      u16* __restrict__ proj){
  const int t = threadIdx.x;
  const int w = t >> 6, L = t & 63;
  const int l16 = L & 15, lq = L >> 4;
  const int m0 = blockIdx.x * 128;
  const int row0 = m0 + w*32;

  f32x4 acc[2][8] = {};
  const u16* Arow0 = qhg + (size_t)(row0 + l16)*DD;
  const u16* Arow1 = Arow0 + (size_t)16*DD;
  #pragma unroll
  for (int ks = 0; ks < 4; ++ks){
    int ko = ks*32 + lq*8;
    union { uint4 u; bf16x8 v; } a0, a1;
    a0.u = *(const uint4*)(Arow0 + ko);
    a1.u = *(const uint4*)(Arow1 + ko);
    #pragma unroll
    for (int nt = 0; nt < 8; ++nt){
      union { uint4 u; bf16x8 v; } bb;
      bb.u = *(const uint4*)(WoT + (size_t)(nt*16 + l16)*DD + ko);
      acc[0][nt] = __builtin_amdgcn_mfma_f32_16x16x32_bf16(a0.v, bb.v, acc[0][nt], 0, 0, 0);
      acc[1][nt] = __builtin_amdgcn_mfma_f32_16x16x32_bf16(a1.v, bb.v, acc[1][nt], 0, 0, 0);
    }
  }
  #pragma unroll
  for (int mt = 0; mt < 2; ++mt)
    #pragma unroll
    for (int r = 0; r < 4; ++r){
      int row = row0 + mt*16 + lq*4 + r;
      u16* dst = proj + (size_t)row*N3;
      #pragma unroll
      for (int nt = 0; nt < 8; ++nt)
        dst[nt*16 + l16] = f2bf(acc[mt][nt][r]);
    }
}

// ---------------- K5: MFMA logits: tanh -> mask -> log_softmax -> gather -> sum ----------------
__global__ __launch_bounds__(256) void k_logits(const u16* __restrict__ proj,
                                                const int* __restrict__ rank,
                                                const int* __restrict__ oa,
                                                float* __restrict__ outlps){
  __shared__ float red[4];
  const int b = blockIdx.x;
  const int t = threadIdx.x;
  const int w = t >> 6, L = t & 63;
  const int l16 = L & 15, lq = L >> 4;
  const float inv_sqrt_d = 0.08838834764831843f;  // 1/sqrt(128)

  const u16* Gbase  = proj + (size_t)b*AA*N3;       // glimpse cols [0..127]
  const u16* LKbase = Gbase + 256;                  // logit_K cols [256..383]

  int ra[13];
  #pragma unroll
  for (int at = 0; at < 13; ++at){
    int a = at*16 + l16;
    ra[at] = (a < AA) ? rank[b*AA + a] : -1;        // -1 => always masked
  }

  float lp_part = 0.f;

  for (int it = w; it < 13; it += 4){
    bf16x8 af[4];
    {
      const u16* arow = Gbase + (size_t)(it*16 + l16)*N3;
      #pragma unroll
      for (int kb = 0; kb < 4; ++kb){
        union { uint4 u; bf16x8 v; } tmp;
        tmp.u = *(const uint4*)(arow + kb*32 + lq*8);
        af[kb] = tmp.v;
      }
    }
    f32x4 S[13];
    #pragma unroll
    for (int at = 0; at < 13; ++at){
      const u16* brow = LKbase + (size_t)(at*16 + l16)*N3;
      f32x4 acc = {0.f,0.f,0.f,0.f};
      #pragma unroll
      for (int kb = 0; kb < 4; ++kb){
        union { uint4 u; bf16x8 v; } tmp;
        tmp.u = *(const uint4*)(brow + kb*32 + lq*8);
        acc = __builtin_amdgcn_mfma_f32_16x16x32_bf16(af[kb], tmp.v, acc, 0, 0, 0);
      }
      S[at] = acc;
    }
    #pragma unroll
    for (int at = 0; at < 13; ++at)
      #pragma unroll
      for (int r = 0; r < 4; ++r){
        int i = it*16 + lq*4 + r;
        float x = S[at][r] * inv_sqrt_d;
        float e = __expf(2.0f*x);
        float th = 1.0f - 2.0f/(e + 1.0f);
        S[at][r] = (ra[at] < i) ? -__builtin_inff() : 10.0f*th;
      }
    #pragma unroll
    for (int r = 0; r < 4; ++r){
      int i = it*16 + lq*4 + r;
      float m = S[0][r];
      #pragma unroll
      for (int at = 1; at < 13; ++at) m = fmaxf(m, S[at][r]);
      #pragma unroll
      for (int off = 1; off < 16; off <<= 1) m = fmaxf(m, __shfl_xor(m, off));
      float sum = 0.f;
      #pragma unroll
      for (int at = 0; at < 13; ++at) sum += __expf(S[at][r] - m);
      #pragma unroll
      for (int off = 1; off < 16; off <<= 1) sum += __shfl_xor(sum, off);
      if (i < AA){
        float lse = m + __logf(sum);
        int act = oa[b*AA + i];
        if ((act & 15) == l16){
          int at0 = act >> 4;
          #pragma unroll
          for (int at = 0; at < 13; ++at)
            if (at == at0) lp_part += S[at][r] - lse;
        }
      }
    }
  }
  #pragma unroll
  for (int off = 1; off < 64; off <<= 1) lp_part += __shfl_xor(lp_part, off);
  if (L == 0) red[w] = lp_part;
  __syncthreads();
  if (t == 0) outlps[b] = red[0] + red[1] + red[2] + red[3];
}

// ---------------- launch ----------------
extern "C" void kernel_launch(void* const* d_in, const int* in_sizes, int n_in,
                              void* d_out, int out_size, void* d_ws, size_t ws_size,
                              hipStream_t stream){
  const float* E  = (const float*)d_in[0];
  const int*   oa = (const int*)d_in[1];
  const float* Wp = (const float*)d_in[2];
  const float* Wn = (const float*)d_in[3];
  const float* Wf = (const float*)d_in[4];
  const float* Ws = (const float*)d_in[5];
  const float* Wo = (const float*)d_in[6];
  float* out = (float*)d_out;

  char* ws = (char*)d_ws;
  int*   rank   = (int*)ws;                     //   819,200 B
  float* fixedc = (float*)(ws + 819200);        //   524,288 B
  u16*   proj   = (u16*)(ws + 1343488);         // 157,286,400 B  [B][A][384] bf16
  u16*   qhg    = (u16*)(ws + 158629888);       //  52,428,800 B  [B][A][128] bf16
  u16*   WnT    = (u16*)(ws + 211058688);       //      98,304 B  [384][128] bf16
  u16*   WsT    = (u16*)(ws + 211156992);       //      32,768 B  [128][128] bf16
  u16*   WoT    = (u16*)(ws + 211189760);       //      32,768 B  [128][128] bf16
  // total workspace: 211,222,528 B

  k_act_rank<<<dim3((BB*AA)/256), 256, 0, stream>>>(oa, out, rank);
  k_prep<<<dim3(320), 256, 0, stream>>>(Wn, Ws, Wo, WnT, WsT, WoT);
  k_fixed<<<dim3(BB), 128, 0, stream>>>(E, Wf, fixedc);
  k_proj_mfma<<<dim3((BB*AA)/128, N3/128), 256, 0, stream>>>(E, WnT, proj);
  k_query_mfma<<<dim3((BB*AA)/128), 256, 0, stream>>>(E, oa, Wp, WsT, fixedc, qhg);
  k_attn<<<dim3(BB, HH), 64, 0, stream>>>(proj, rank, qhg);
  k_glimpse_mfma<<<dim3((BB*AA)/128), 256, 0, stream>>>(qhg, WoT, proj);
  k_logits<<<dim3(BB), 256, 0, stream>>>(proj, rank, oa, out + BB*AA);
}

// Round 6
// 830.726 us; speedup vs baseline: 4.3053x; 1.0865x over previous
//
#include <hip/hip_runtime.h>
#include <cstdint>
#include <cstddef>

#define BB 1024
#define AA 200
#define DD 128
#define HH 8
#define N3 384

typedef unsigned short u16;
typedef unsigned int u32;
typedef __attribute__((ext_vector_type(8))) short bf16x8;
typedef __attribute__((ext_vector_type(4))) float f32x4;

__device__ __forceinline__ float bf2f(u16 v){ return __uint_as_float(((u32)v) << 16); }
__device__ __forceinline__ u16 f2bf(float f){
  u32 u = __float_as_uint(f);
  u32 r = u + 0x7fffu + ((u >> 16) & 1u);
  return (u16)(r >> 16);
}
__device__ __forceinline__ bf16x8 pack8(float4 a, float4 b){
  bf16x8 o;
  o[0] = (short)f2bf(a.x); o[1] = (short)f2bf(a.y);
  o[2] = (short)f2bf(a.z); o[3] = (short)f2bf(a.w);
  o[4] = (short)f2bf(b.x); o[5] = (short)f2bf(b.y);
  o[6] = (short)f2bf(b.z); o[7] = (short)f2bf(b.w);
  return o;
}

// ---------------- K0: copy old_action to out (as float) + build rank ----------------
__global__ void k_act_rank(const int* __restrict__ oa, float* __restrict__ out0,
                           int* __restrict__ rank){
  int m = blockIdx.x * 256 + threadIdx.x;
  if (m >= BB*AA) return;
  int v = oa[m];
  out0[m] = (float)v;
  int b = m / AA;
  int j = m - b*AA;
  rank[b*AA + v] = j;
}

// ---------------- K0b: transpose+cast weights to bf16 [n][k] ----------------
__global__ void k_prep(const float* __restrict__ Wn, const float* __restrict__ Ws,
                       const float* __restrict__ Wo,
                       u16* __restrict__ WnT, u16* __restrict__ WsT,
                       u16* __restrict__ WoT){
  int idx = blockIdx.x * 256 + threadIdx.x;
  if (idx < 49152){                       // WnT: [384][128]
    int n = idx >> 7, k = idx & 127;
    WnT[idx] = f2bf(Wn[k*N3 + n]);
  } else if (idx < 65536){                // WsT: [128][128]
    int j = idx - 49152;
    int n = j >> 7, k = j & 127;
    WsT[j] = f2bf(Ws[k*DD + n]);
  } else if (idx < 81920){                // WoT: [128][128]
    int j = idx - 65536;
    int n = j >> 7, k = j & 127;
    WoT[j] = f2bf(Wo[k*DD + n]);
  }
}

// ---------------- K1: fixed_ctx = mean_a(E[b]) @ W_fixed ----------------
__global__ void k_fixed(const float* __restrict__ E, const float* __restrict__ Wf,
                        float* __restrict__ fixedc){
  int b = blockIdx.x;
  int d = threadIdx.x;              // 128 threads
  __shared__ float ge[DD];
  const float* Eb = E + (size_t)b*AA*DD;
  float s = 0.f;
  for (int a = 0; a < AA; ++a) s += Eb[a*DD + d];
  ge[d] = s * (1.0f/AA);
  __syncthreads();
  float acc = 0.f;
  for (int k = 0; k < DD; ++k) acc = fmaf(ge[k], Wf[k*DD + d], acc);
  fixedc[b*DD + d] = acc;
}

// ---------------- K2a: proj = E @ W_node via MFMA (block 128x128, wave 32x128) ----------------
__global__ __launch_bounds__(256) void k_proj_mfma(const float* __restrict__ E,
                                                   const u16* __restrict__ WnT,
                                                   u16* __restrict__ proj){
  const int t = threadIdx.x;
  const int w = t >> 6, L = t & 63;
  const int l16 = L & 15, lq = L >> 4;
  const int m0 = blockIdx.x * 128;
  const int n0 = blockIdx.y * 128;
  const int row0 = m0 + w*32;

  f32x4 acc[2][8] = {};
  const float* Arow0 = E + (size_t)(row0 + l16)*DD;
  const float* Arow1 = Arow0 + (size_t)16*DD;
  #pragma unroll
  for (int ks = 0; ks < 4; ++ks){
    int ko = ks*32 + lq*8;
    bf16x8 a0 = pack8(*(const float4*)(Arow0 + ko), *(const float4*)(Arow0 + ko + 4));
    bf16x8 a1 = pack8(*(const float4*)(Arow1 + ko), *(const float4*)(Arow1 + ko + 4));
    #pragma unroll
    for (int nt = 0; nt < 8; ++nt){
      union { uint4 u; bf16x8 v; } bb;
      bb.u = *(const uint4*)(WnT + (size_t)(n0 + nt*16 + l16)*DD + ko);
      acc[0][nt] = __builtin_amdgcn_mfma_f32_16x16x32_bf16(a0, bb.v, acc[0][nt], 0, 0, 0);
      acc[1][nt] = __builtin_amdgcn_mfma_f32_16x16x32_bf16(a1, bb.v, acc[1][nt], 0, 0, 0);
    }
  }
  #pragma unroll
  for (int mt = 0; mt < 2; ++mt)
    #pragma unroll
    for (int r = 0; r < 4; ++r){
      int row = row0 + mt*16 + lq*4 + r;
      u16* dst = proj + (size_t)row*N3 + n0;
      #pragma unroll
      for (int nt = 0; nt < 8; ++nt)
        dst[nt*16 + l16] = f2bf(acc[mt][nt][r]);
    }
}

// ---------------- K2b: query = fixed_ctx + gather(E,prev) @ W_step via MFMA ----------------
__global__ __launch_bounds__(256) void k_query_mfma(const float* __restrict__ E,
                                                    const int* __restrict__ oa,
                                                    const float* __restrict__ Wp,
                                                    const u16* __restrict__ WsT,
                                                    const float* __restrict__ fixedc,
                                                    u16* __restrict__ qhg){
  const int t = threadIdx.x;
  const int w = t >> 6, L = t & 63;
  const int l16 = L & 15, lq = L >> 4;
  const int m0 = blockIdx.x * 128;
  const int row0 = m0 + w*32;

  const float* src[2];
  #pragma unroll
  for (int mt = 0; mt < 2; ++mt){
    int q = row0 + mt*16 + l16;
    int b = q / AA, i = q - b*AA;
    src[mt] = (i == 0) ? Wp : (E + (size_t)(b*AA + oa[b*AA + i - 1])*DD);
  }

  f32x4 acc[2][8] = {};
  #pragma unroll
  for (int ks = 0; ks < 4; ++ks){
    int ko = ks*32 + lq*8;
    bf16x8 a0 = pack8(*(const float4*)(src[0] + ko), *(const float4*)(src[0] + ko + 4));
    bf16x8 a1 = pack8(*(const float4*)(src[1] + ko), *(const float4*)(src[1] + ko + 4));
    #pragma unroll
    for (int nt = 0; nt < 8; ++nt){
      union { uint4 u; bf16x8 v; } bb;
      bb.u = *(const uint4*)(WsT + (size_t)(nt*16 + l16)*DD + ko);
      acc[0][nt] = __builtin_amdgcn_mfma_f32_16x16x32_bf16(a0, bb.v, acc[0][nt], 0, 0, 0);
      acc[1][nt] = __builtin_amdgcn_mfma_f32_16x16x32_bf16(a1, bb.v, acc[1][nt], 0, 0, 0);
    }
  }
  #pragma unroll
  for (int mt = 0; mt < 2; ++mt)
    #pragma unroll
    for (int r = 0; r < 4; ++r){
      int row = row0 + mt*16 + lq*4 + r;
      int b = row / AA;
      const float* fc = fixedc + (size_t)b*DD;
      u16* dst = qhg + (size_t)row*DD;
      #pragma unroll
      for (int nt = 0; nt < 8; ++nt)
        dst[nt*16 + l16] = f2bf(acc[mt][nt][r] + fc[nt*16 + l16]);
    }
}

// ---------------- K3: MFMA attention, one wave per (b, head) ----------------
// K staged in LDS (was: re-fetched from global 13x). Softmax normalization
// deferred to the PV accumulator (saves 52 muls/it).
#define KSTR 24    // u16 stride: 48-B rows, 16-B aligned, <=2-way banks
#define VSTR 232   // u16 stride for VT/P
__global__ __launch_bounds__(64) void k_attn(const u16* __restrict__ proj,
                                             const int* __restrict__ rank,
                                             u16* __restrict__ qhg){
  __shared__ __align__(16) u16 KL[208*KSTR];  // [a][d], rows >=200 zero
  __shared__ __align__(16) u16 VT[16*VSTR];   // [d][a], cols >=200 zero
  __shared__ __align__(16) u16 P [16*VSTR];   // [i_loc][a]
  const int b = blockIdx.x;
  const int h = blockIdx.y;
  const int L = threadIdx.x;       // 0..63
  const int l16 = L & 15, lq = L >> 4;

  for (int idx = L; idx < 208*KSTR; idx += 64) KL[idx] = 0;
  for (int idx = L; idx < 16*VSTR; idx += 64){ VT[idx] = 0; P[idx] = 0; }
  __syncthreads();

  // stage K rows + V transposed
  for (int a = L; a < AA; a += 64){
    const u16* src = proj + ((size_t)(b*AA + a))*N3 + h*16;   // gK
    uint4 k0 = *(const uint4*)(src);
    uint4 k1 = *(const uint4*)(src + 8);
    *(uint4*)&KL[a*KSTR]     = k0;
    *(uint4*)&KL[a*KSTR + 8] = k1;
    const u16* sv = src + 128;                                // gV
    u16 d16[16];
    *(uint4*)(d16)   = *(const uint4*)(sv);
    *(uint4*)(d16+8) = *(const uint4*)(sv+8);
    #pragma unroll
    for (int d = 0; d < 16; ++d) VT[d*VSTR + a] = d16[d];
  }

  int ra[13];
  #pragma unroll
  for (int at = 0; at < 13; ++at){
    int a = at*16 + l16;
    ra[at] = (a < AA) ? rank[b*AA + a] : -1;
  }
  __syncthreads();

  u16* Qbase = qhg + (size_t)b*AA*DD + h*16;

  const bf16x8 zf = {0,0,0,0,0,0,0,0};
  for (int it = 0; it < 13; ++it){
    // A-frag: Q[i=it*16+l16][d=lq*8+j] (d>=16 zero, i>=200 pad)
    bf16x8 qf = zf;
    int qi = it*16 + l16;
    if (lq < 2 && qi < AA){
      union { uint4 u; bf16x8 v; } tmp;
      tmp.u = *(const uint4*)(Qbase + (size_t)qi*DD + lq*8);
      qf = tmp.v;
    }
    // S tiles from LDS K
    f32x4 S[13];
    #pragma unroll
    for (int at = 0; at < 13; ++at){
      bf16x8 kf = zf;
      if (lq < 2){
        union { uint4 u; bf16x8 v; } tmp;
        tmp.u = *(const uint4*)&KL[(at*16 + l16)*KSTR + lq*8];
        kf = tmp.v;
      }
      f32x4 z = {0.f,0.f,0.f,0.f};
      S[at] = __builtin_amdgcn_mfma_f32_16x16x32_bf16(qf, kf, z, 0, 0, 0);
    }
    // scale + mask
    #pragma unroll
    for (int at = 0; at < 13; ++at)
      #pragma unroll
      for (int r = 0; r < 4; ++r){
        int i = it*16 + lq*4 + r;
        float v = S[at][r] * 0.25f;
        S[at][r] = (ra[at] < i) ? -__builtin_inff() : v;
      }
    // softmax over a: compute e-values + per-row 1/sum (normalize after PV)
    float inv[4];
    #pragma unroll
    for (int r = 0; r < 4; ++r){
      float m = S[0][r];
      #pragma unroll
      for (int at = 1; at < 13; ++at) m = fmaxf(m, S[at][r]);
      #pragma unroll
      for (int off = 1; off < 16; off <<= 1) m = fmaxf(m, __shfl_xor(m, off));
      float sum = 0.f;
      #pragma unroll
      for (int at = 0; at < 13; ++at){
        float e = __expf(S[at][r] - m);
        S[at][r] = e; sum += e;
      }
      #pragma unroll
      for (int off = 1; off < 16; off <<= 1) sum += __shfl_xor(sum, off);
      inv[r] = 1.0f / sum;
    }
    // P (unnormalized e) -> LDS [i_loc][a]
    #pragma unroll
    for (int at = 0; at < 13; ++at)
      #pragma unroll
      for (int r = 0; r < 4; ++r)
        P[(lq*4 + r)*VSTR + at*16 + l16] = f2bf(S[at][r]);
    __syncthreads();
    // H = P V, then scale rows by inv
    f32x4 acc = {0.f,0.f,0.f,0.f};
    #pragma unroll
    for (int kb = 0; kb < 7; ++kb){
      union { uint4 u; bf16x8 v; } pa, vb;
      pa.u = *(const uint4*)&P [l16*VSTR + kb*32 + lq*8];
      vb.u = *(const uint4*)&VT[l16*VSTR + kb*32 + lq*8];
      acc = __builtin_amdgcn_mfma_f32_16x16x32_bf16(pa.v, vb.v, acc, 0, 0, 0);
    }
    #pragma unroll
    for (int r = 0; r < 4; ++r){
      int i = it*16 + lq*4 + r;
      if (i < AA) Qbase[(size_t)i*DD + l16] = f2bf(acc[r] * inv[r]);
    }
    __syncthreads();
  }
}

// ---------------- K4: glimpse = heads @ W_out via MFMA -> proj cols [0..127] ----------------
__global__ __launch_bounds__(256) void k_glimpse_mfma(const u16* __restrict__ qhg,
                                                      const u16* __restrict__ WoT,
                                                      u16* __restrict__ proj){
  const int t = threadIdx.x;
  const int w = t >> 6, L = t & 63;
  const int l16 = L & 15, lq = L >> 4;
  const int m0 = blockIdx.x * 128;
  const int row0 = m0 + w*32;

  f32x4 acc[2][8] = {};
  const u16* Arow0 = qhg + (size_t)(row0 + l16)*DD;
  const u16* Arow1 = Arow0 + (size_t)16*DD;
  #pragma unroll
  for (int ks = 0; ks < 4; ++ks){
    int ko = ks*32 + lq*8;
    union { uint4 u; bf16x8 v; } a0, a1;
    a0.u = *(const uint4*)(Arow0 + ko);
    a1.u = *(const uint4*)(Arow1 + ko);
    #pragma unroll
    for (int nt = 0; nt < 8; ++nt){
      union { uint4 u; bf16x8 v; } bb;
      bb.u = *(const uint4*)(WoT + (size_t)(nt*16 + l16)*DD + ko);
      acc[0][nt] = __builtin_amdgcn_mfma_f32_16x16x32_bf16(a0.v, bb.v, acc[0][nt], 0, 0, 0);
      acc[1][nt] = __builtin_amdgcn_mfma_f32_16x16x32_bf16(a1.v, bb.v, acc[1][nt], 0, 0, 0);
    }
  }
  #pragma unroll
  for (int mt = 0; mt < 2; ++mt)
    #pragma unroll
    for (int r = 0; r < 4; ++r){
      int row = row0 + mt*16 + lq*4 + r;
      u16* dst = proj + (size_t)row*N3;
      #pragma unroll
      for (int nt = 0; nt < 8; ++nt)
        dst[nt*16 + l16] = f2bf(acc[mt][nt][r]);
    }
}

// ---------------- K5: MFMA logits: tanh -> mask -> log_softmax -> gather -> sum ----------------
__global__ __launch_bounds__(256) void k_logits(const u16* __restrict__ proj,
                                                const int* __restrict__ rank,
                                                const int* __restrict__ oa,
                                                float* __restrict__ outlps){
  __shared__ float red[4];
  const int b = blockIdx.x;
  const int t = threadIdx.x;
  const int w = t >> 6, L = t & 63;
  const int l16 = L & 15, lq = L >> 4;
  const float inv_sqrt_d = 0.08838834764831843f;  // 1/sqrt(128)

  const u16* Gbase  = proj + (size_t)b*AA*N3;       // glimpse cols [0..127]
  const u16* LKbase = Gbase + 256;                  // logit_K cols [256..383]

  int ra[13];
  #pragma unroll
  for (int at = 0; at < 13; ++at){
    int a = at*16 + l16;
    ra[at] = (a < AA) ? rank[b*AA + a] : -1;        // -1 => always masked
  }

  float lp_part = 0.f;

  for (int it = w; it < 13; it += 4){
    bf16x8 af[4];
    {
      const u16* arow = Gbase + (size_t)(it*16 + l16)*N3;
      #pragma unroll
      for (int kb = 0; kb < 4; ++kb){
        union { uint4 u; bf16x8 v; } tmp;
        tmp.u = *(const uint4*)(arow + kb*32 + lq*8);
        af[kb] = tmp.v;
      }
    }
    f32x4 S[13];
    #pragma unroll
    for (int at = 0; at < 13; ++at){
      const u16* brow = LKbase + (size_t)(at*16 + l16)*N3;
      f32x4 acc = {0.f,0.f,0.f,0.f};
      #pragma unroll
      for (int kb = 0; kb < 4; ++kb){
        union { uint4 u; bf16x8 v; } tmp;
        tmp.u = *(const uint4*)(brow + kb*32 + lq*8);
        acc = __builtin_amdgcn_mfma_f32_16x16x32_bf16(af[kb], tmp.v, acc, 0, 0, 0);
      }
      S[at] = acc;
    }
    #pragma unroll
    for (int at = 0; at < 13; ++at)
      #pragma unroll
      for (int r = 0; r < 4; ++r){
        int i = it*16 + lq*4 + r;
        float x = S[at][r] * inv_sqrt_d;
        float e = __expf(2.0f*x);
        float th = 1.0f - 2.0f/(e + 1.0f);
        S[at][r] = (ra[at] < i) ? -__builtin_inff() : 10.0f*th;
      }
    #pragma unroll
    for (int r = 0; r < 4; ++r){
      int i = it*16 + lq*4 + r;
      float m = S[0][r];
      #pragma unroll
      for (int at = 1; at < 13; ++at) m = fmaxf(m, S[at][r]);
      #pragma unroll
      for (int off = 1; off < 16; off <<= 1) m = fmaxf(m, __shfl_xor(m, off));
      float sum = 0.f;
      #pragma unroll
      for (int at = 0; at < 13; ++at) sum += __expf(S[at][r] - m);
      #pragma unroll
      for (int off = 1; off < 16; off <<= 1) sum += __shfl_xor(sum, off);
      if (i < AA){
        float lse = m + __logf(sum);
        int act = oa[b*AA + i];
        if ((act & 15) == l16){
          int at0 = act >> 4;
          #pragma unroll
          for (int at = 0; at < 13; ++at)
            if (at == at0) lp_part += S[at][r] - lse;
        }
      }
    }
  }
  #pragma unroll
  for (int off = 1; off < 64; off <<= 1) lp_part += __shfl_xor(lp_part, off);
  if (L == 0) red[w] = lp_part;
  __syncthreads();
  if (t == 0) outlps[b] = red[0] + red[1] + red[2] + red[3];
}

// ---------------- launch ----------------
extern "C" void kernel_launch(void* const* d_in, const int* in_sizes, int n_in,
                              void* d_out, int out_size, void* d_ws, size_t ws_size,
                              hipStream_t stream){
  const float* E  = (const float*)d_in[0];
  const int*   oa = (const int*)d_in[1];
  const float* Wp = (const float*)d_in[2];
  const float* Wn = (const float*)d_in[3];
  const float* Wf = (const float*)d_in[4];
  const float* Ws = (const float*)d_in[5];
  const float* Wo = (const float*)d_in[6];
  float* out = (float*)d_out;

  char* ws = (char*)d_ws;
  int*   rank   = (int*)ws;                     //   819,200 B
  float* fixedc = (float*)(ws + 819200);        //   524,288 B
  u16*   proj   = (u16*)(ws + 1343488);         // 157,286,400 B  [B][A][384] bf16
  u16*   qhg    = (u16*)(ws + 158629888);       //  52,428,800 B  [B][A][128] bf16
  u16*   WnT    = (u16*)(ws + 211058688);       //      98,304 B  [384][128] bf16
  u16*   WsT    = (u16*)(ws + 211156992);       //      32,768 B  [128][128] bf16
  u16*   WoT    = (u16*)(ws + 211189760);       //      32,768 B  [128][128] bf16
  // total workspace: 211,222,528 B

  k_act_rank<<<dim3((BB*AA)/256), 256, 0, stream>>>(oa, out, rank);
  k_prep<<<dim3(320), 256, 0, stream>>>(Wn, Ws, Wo, WnT, WsT, WoT);
  k_fixed<<<dim3(BB), 128, 0, stream>>>(E, Wf, fixedc);
  k_proj_mfma<<<dim3((BB*AA)/128, N3/128), 256, 0, stream>>>(E, WnT, proj);
  k_query_mfma<<<dim3((BB*AA)/128), 256, 0, stream>>>(E, oa, Wp, WsT, fixedc, qhg);
  k_attn<<<dim3(BB, HH), 64, 0, stream>>>(proj, rank, qhg);
  k_glimpse_mfma<<<dim3((BB*AA)/128), 256, 0, stream>>>(qhg, WoT, proj);
  k_logits<<<dim3(BB), 256, 0, stream>>>(proj, rank, oa, out + BB*AA);
}

// Round 7
// 740.312 us; speedup vs baseline: 4.8311x; 1.1221x over previous
//
#include <hip/hip_runtime.h>
#include <cstdint>
#include <cstddef>

#define BB 1024
#define AA 200
#define DD 128
#define HH 8
#define N3 384

typedef unsigned short u16;
typedef unsigned int u32;
typedef __attribute__((ext_vector_type(8))) short bf16x8;
typedef __attribute__((ext_vector_type(4))) float f32x4;

__device__ __forceinline__ float bf2f(u16 v){ return __uint_as_float(((u32)v) << 16); }
__device__ __forceinline__ u16 f2bf(float f){
  u32 u = __float_as_uint(f);
  u32 r = u + 0x7fffu + ((u >> 16) & 1u);
  return (u16)(r >> 16);
}
__device__ __forceinline__ u16 f2bf_trunc(float f){
  return (u16)(__float_as_uint(f) >> 16);
}
__device__ __forceinline__ bf16x8 pack8(float4 a, float4 b){
  bf16x8 o;
  o[0] = (short)f2bf(a.x); o[1] = (short)f2bf(a.y);
  o[2] = (short)f2bf(a.z); o[3] = (short)f2bf(a.w);
  o[4] = (short)f2bf(b.x); o[5] = (short)f2bf(b.y);
  o[6] = (short)f2bf(b.z); o[7] = (short)f2bf(b.w);
  return o;
}

// ---------------- K0: copy old_action to out (as float) + build rank ----------------
__global__ void k_act_rank(const int* __restrict__ oa, float* __restrict__ out0,
                           int* __restrict__ rank){
  int m = blockIdx.x * 256 + threadIdx.x;
  if (m >= BB*AA) return;
  int v = oa[m];
  out0[m] = (float)v;
  int b = m / AA;
  int j = m - b*AA;
  rank[b*AA + v] = j;
}

// ---------------- K0b: transpose+cast weights to bf16 [n][k] ----------------
__global__ void k_prep(const float* __restrict__ Wn, const float* __restrict__ Ws,
                       const float* __restrict__ Wo,
                       u16* __restrict__ WnT, u16* __restrict__ WsT,
                       u16* __restrict__ WoT){
  int idx = blockIdx.x * 256 + threadIdx.x;
  if (idx < 49152){                       // WnT: [384][128]
    int n = idx >> 7, k = idx & 127;
    WnT[idx] = f2bf(Wn[k*N3 + n]);
  } else if (idx < 65536){                // WsT: [128][128]
    int j = idx - 49152;
    int n = j >> 7, k = j & 127;
    WsT[j] = f2bf(Ws[k*DD + n]);
  } else if (idx < 81920){                // WoT: [128][128]
    int j = idx - 65536;
    int n = j >> 7, k = j & 127;
    WoT[j] = f2bf(Wo[k*DD + n]);
  }
}

// ---------------- K1: fixed_ctx = mean_a(E[b]) @ W_fixed ----------------
__global__ void k_fixed(const float* __restrict__ E, const float* __restrict__ Wf,
                        float* __restrict__ fixedc){
  int b = blockIdx.x;
  int d = threadIdx.x;              // 128 threads
  __shared__ float ge[DD];
  const float* Eb = E + (size_t)b*AA*DD;
  float s = 0.f;
  for (int a = 0; a < AA; ++a) s += Eb[a*DD + d];
  ge[d] = s * (1.0f/AA);
  __syncthreads();
  float acc = 0.f;
  for (int k = 0; k < DD; ++k) acc = fmaf(ge[k], Wf[k*DD + d], acc);
  fixedc[b*DD + d] = acc;
}

// ---------------- K2a: proj = E @ W_node via MFMA (block 128x128, wave 32x128) ----------------
__global__ __launch_bounds__(256) void k_proj_mfma(const float* __restrict__ E,
                                                   const u16* __restrict__ WnT,
                                                   u16* __restrict__ proj){
  const int t = threadIdx.x;
  const int w = t >> 6, L = t & 63;
  const int l16 = L & 15, lq = L >> 4;
  const int m0 = blockIdx.x * 128;
  const int n0 = blockIdx.y * 128;
  const int row0 = m0 + w*32;

  f32x4 acc[2][8] = {};
  const float* Arow0 = E + (size_t)(row0 + l16)*DD;
  const float* Arow1 = Arow0 + (size_t)16*DD;
  #pragma unroll
  for (int ks = 0; ks < 4; ++ks){
    int ko = ks*32 + lq*8;
    bf16x8 a0 = pack8(*(const float4*)(Arow0 + ko), *(const float4*)(Arow0 + ko + 4));
    bf16x8 a1 = pack8(*(const float4*)(Arow1 + ko), *(const float4*)(Arow1 + ko + 4));
    #pragma unroll
    for (int nt = 0; nt < 8; ++nt){
      union { uint4 u; bf16x8 v; } bb;
      bb.u = *(const uint4*)(WnT + (size_t)(n0 + nt*16 + l16)*DD + ko);
      acc[0][nt] = __builtin_amdgcn_mfma_f32_16x16x32_bf16(a0, bb.v, acc[0][nt], 0, 0, 0);
      acc[1][nt] = __builtin_amdgcn_mfma_f32_16x16x32_bf16(a1, bb.v, acc[1][nt], 0, 0, 0);
    }
  }
  #pragma unroll
  for (int mt = 0; mt < 2; ++mt)
    #pragma unroll
    for (int r = 0; r < 4; ++r){
      int row = row0 + mt*16 + lq*4 + r;
      u16* dst = proj + (size_t)row*N3 + n0;
      #pragma unroll
      for (int nt = 0; nt < 8; ++nt)
        dst[nt*16 + l16] = f2bf(acc[mt][nt][r]);
    }
}

// ---------------- K2b: query = (fixed_ctx + gather(E,prev) @ W_step) * 0.25 via MFMA ----------------
// NOTE: 1/sqrt(dh)=0.25 folded into the stored query (qhg consumed only by k_attn QK^T).
__global__ __launch_bounds__(256) void k_query_mfma(const float* __restrict__ E,
                                                    const int* __restrict__ oa,
                                                    const float* __restrict__ Wp,
                                                    const u16* __restrict__ WsT,
                                                    const float* __restrict__ fixedc,
                                                    u16* __restrict__ qhg){
  const int t = threadIdx.x;
  const int w = t >> 6, L = t & 63;
  const int l16 = L & 15, lq = L >> 4;
  const int m0 = blockIdx.x * 128;
  const int row0 = m0 + w*32;

  const float* src[2];
  #pragma unroll
  for (int mt = 0; mt < 2; ++mt){
    int q = row0 + mt*16 + l16;
    int b = q / AA, i = q - b*AA;
    src[mt] = (i == 0) ? Wp : (E + (size_t)(b*AA + oa[b*AA + i - 1])*DD);
  }

  f32x4 acc[2][8] = {};
  #pragma unroll
  for (int ks = 0; ks < 4; ++ks){
    int ko = ks*32 + lq*8;
    bf16x8 a0 = pack8(*(const float4*)(src[0] + ko), *(const float4*)(src[0] + ko + 4));
    bf16x8 a1 = pack8(*(const float4*)(src[1] + ko), *(const float4*)(src[1] + ko + 4));
    #pragma unroll
    for (int nt = 0; nt < 8; ++nt){
      union { uint4 u; bf16x8 v; } bb;
      bb.u = *(const uint4*)(WsT + (size_t)(nt*16 + l16)*DD + ko);
      acc[0][nt] = __builtin_amdgcn_mfma_f32_16x16x32_bf16(a0, bb.v, acc[0][nt], 0, 0, 0);
      acc[1][nt] = __builtin_amdgcn_mfma_f32_16x16x32_bf16(a1, bb.v, acc[1][nt], 0, 0, 0);
    }
  }
  #pragma unroll
  for (int mt = 0; mt < 2; ++mt)
    #pragma unroll
    for (int r = 0; r < 4; ++r){
      int row = row0 + mt*16 + lq*4 + r;
      int b = row / AA;
      const float* fc = fixedc + (size_t)b*DD;
      u16* dst = qhg + (size_t)row*DD;
      #pragma unroll
      for (int nt = 0; nt < 8; ++nt)
        dst[nt*16 + l16] = f2bf((acc[mt][nt][r] + fc[nt*16 + l16]) * 0.25f);
    }
}

// ---------------- K3: MFMA attention, 4 waves per (b, head) block ----------------
// K/V staged once by all 4 waves; each wave owns a private P and processes
// i-tiles it = w, w+4, ... with NO barriers in the main loop.
#define KSTR 24    // u16 stride: 48-B rows, 16-B aligned
#define VSTR 232   // u16 stride for VT/P (116 dwords -> <=2-way banks on b128)
__global__ __launch_bounds__(256) void k_attn(const u16* __restrict__ proj,
                                              const int* __restrict__ rank,
                                              u16* __restrict__ qhg){
  __shared__ __align__(16) u16 KL[208*KSTR];     // [a][d], rows >=200 zero
  __shared__ __align__(16) u16 VT[16*VSTR];      // [d][a], cols >=200 zero
  __shared__ __align__(16) u16 P [4][16*VSTR];   // per-wave [i_loc][a]
  const int b = blockIdx.x;
  const int h = blockIdx.y;
  const int t = threadIdx.x;
  const int w = t >> 6, L = t & 63;
  const int l16 = L & 15, lq = L >> 4;

  for (int idx = t; idx < 208*KSTR; idx += 256) KL[idx] = 0;
  for (int idx = t; idx < 16*VSTR; idx += 256) VT[idx] = 0;
  {
    u16* Pw = P[w];
    for (int idx = L; idx < 16*VSTR; idx += 64) Pw[idx] = 0;
  }

  // stage K rows + V transposed (cooperative across 256 threads)
  if (t < AA){
    const u16* src = proj + ((size_t)(b*AA + t))*N3 + h*16;   // gK
    uint4 k0 = *(const uint4*)(src);
    uint4 k1 = *(const uint4*)(src + 8);
    *(uint4*)&KL[t*KSTR]     = k0;
    *(uint4*)&KL[t*KSTR + 8] = k1;
    const u16* sv = src + 128;                                // gV
    u16 d16[16];
    *(uint4*)(d16)   = *(const uint4*)(sv);
    *(uint4*)(d16+8) = *(const uint4*)(sv+8);
    #pragma unroll
    for (int d = 0; d < 16; ++d) VT[d*VSTR + t] = d16[d];
  }

  int ra[13];
  #pragma unroll
  for (int at = 0; at < 13; ++at){
    int a = at*16 + l16;
    ra[at] = (a < AA) ? rank[b*AA + a] : -1;
  }
  __syncthreads();

  u16* Qbase = qhg + (size_t)b*AA*DD + h*16;
  u16* Pw = P[w];

  const bf16x8 zf = {0,0,0,0,0,0,0,0};
  for (int it = w; it < 13; it += 4){
    // A-frag: Q[i=it*16+l16][d=lq*8+j] (d>=16 zero, i>=200 pad); Q pre-scaled by 0.25
    bf16x8 qf = zf;
    int qi = it*16 + l16;
    if (lq < 2 && qi < AA){
      union { uint4 u; bf16x8 v; } tmp;
      tmp.u = *(const uint4*)(Qbase + (size_t)qi*DD + lq*8);
      qf = tmp.v;
    }
    // S tiles from LDS K
    f32x4 S[13];
    #pragma unroll
    for (int at = 0; at < 13; ++at){
      bf16x8 kf = zf;
      if (lq < 2){
        union { uint4 u; bf16x8 v; } tmp;
        tmp.u = *(const uint4*)&KL[(at*16 + l16)*KSTR + lq*8];
        kf = tmp.v;
      }
      f32x4 z = {0.f,0.f,0.f,0.f};
      S[at] = __builtin_amdgcn_mfma_f32_16x16x32_bf16(qf, kf, z, 0, 0, 0);
    }
    // mask (scale already folded into Q)
    #pragma unroll
    for (int at = 0; at < 13; ++at)
      #pragma unroll
      for (int r = 0; r < 4; ++r){
        int i = it*16 + lq*4 + r;
        S[at][r] = (ra[at] < i) ? -__builtin_inff() : S[at][r];
      }
    // softmax over a: e-values + per-row 1/sum (normalize after PV)
    float inv[4];
    #pragma unroll
    for (int r = 0; r < 4; ++r){
      float m = S[0][r];
      #pragma unroll
      for (int at = 1; at < 13; ++at) m = fmaxf(m, S[at][r]);
      #pragma unroll
      for (int off = 1; off < 16; off <<= 1) m = fmaxf(m, __shfl_xor(m, off));
      float sum = 0.f;
      #pragma unroll
      for (int at = 0; at < 13; ++at){
        float e = __expf(S[at][r] - m);
        S[at][r] = e; sum += e;
      }
      #pragma unroll
      for (int off = 1; off < 16; off <<= 1) sum += __shfl_xor(sum, off);
      inv[r] = 1.0f / sum;
    }
    // P (unnormalized e, truncated bf16) -> private LDS [i_loc][a]
    #pragma unroll
    for (int at = 0; at < 13; ++at)
      #pragma unroll
      for (int r = 0; r < 4; ++r)
        Pw[(lq*4 + r)*VSTR + at*16 + l16] = f2bf_trunc(S[at][r]);
    // H = P V, then scale rows by inv (own-wave LDS dependency: no barrier)
    f32x4 acc = {0.f,0.f,0.f,0.f};
    #pragma unroll
    for (int kb = 0; kb < 7; ++kb){
      union { uint4 u; bf16x8 v; } pa, vb;
      pa.u = *(const uint4*)&Pw[l16*VSTR + kb*32 + lq*8];
      vb.u = *(const uint4*)&VT[l16*VSTR + kb*32 + lq*8];
      acc = __builtin_amdgcn_mfma_f32_16x16x32_bf16(pa.v, vb.v, acc, 0, 0, 0);
    }
    #pragma unroll
    for (int r = 0; r < 4; ++r){
      int i = it*16 + lq*4 + r;
      if (i < AA) Qbase[(size_t)i*DD + l16] = f2bf(acc[r] * inv[r]);
    }
  }
}

// ---------------- K4: glimpse = heads @ W_out via MFMA -> proj cols [0..127] ----------------
__global__ __launch_bounds__(256) void k_glimpse_mfma(const u16* __restrict__ qhg,
                                                      const u16* __restrict__ WoT,
                                                      u16* __restrict__ proj){
  const int t = threadIdx.x;
  const int w = t >> 6, L = t & 63;
  const int l16 = L & 15, lq = L >> 4;
  const int m0 = blockIdx.x * 128;
  const int row0 = m0 + w*32;

  f32x4 acc[2][8] = {};
  const u16* Arow0 = qhg + (size_t)(row0 + l16)*DD;
  const u16* Arow1 = Arow0 + (size_t)16*DD;
  #pragma unroll
  for (int ks = 0; ks < 4; ++ks){
    int ko = ks*32 + lq*8;
    union { uint4 u; bf16x8 v; } a0, a1;
    a0.u = *(const uint4*)(Arow0 + ko);
    a1.u = *(const uint4*)(Arow1 + ko);
    #pragma unroll
    for (int nt = 0; nt < 8; ++nt){
      union { uint4 u; bf16x8 v; } bb;
      bb.u = *(const uint4*)(WoT + (size_t)(nt*16 + l16)*DD + ko);
      acc[0][nt] = __builtin_amdgcn_mfma_f32_16x16x32_bf16(a0.v, bb.v, acc[0][nt], 0, 0, 0);
      acc[1][nt] = __builtin_amdgcn_mfma_f32_16x16x32_bf16(a1.v, bb.v, acc[1][nt], 0, 0, 0);
    }
  }
  #pragma unroll
  for (int mt = 0; mt < 2; ++mt)
    #pragma unroll
    for (int r = 0; r < 4; ++r){
      int row = row0 + mt*16 + lq*4 + r;
      u16* dst = proj + (size_t)row*N3;
      #pragma unroll
      for (int nt = 0; nt < 8; ++nt)
        dst[nt*16 + l16] = f2bf(acc[mt][nt][r]);
    }
}

// ---------------- K5: MFMA logits: tanh -> mask -> log_softmax -> gather -> sum ----------------
__global__ __launch_bounds__(256) void k_logits(const u16* __restrict__ proj,
                                                const int* __restrict__ rank,
                                                const int* __restrict__ oa,
                                                float* __restrict__ outlps){
  __shared__ float red[4];
  const int b = blockIdx.x;
  const int t = threadIdx.x;
  const int w = t >> 6, L = t & 63;
  const int l16 = L & 15, lq = L >> 4;
  const float inv_sqrt_d = 0.08838834764831843f;  // 1/sqrt(128)

  const u16* Gbase  = proj + (size_t)b*AA*N3;       // glimpse cols [0..127]
  const u16* LKbase = Gbase + 256;                  // logit_K cols [256..383]

  int ra[13];
  #pragma unroll
  for (int at = 0; at < 13; ++at){
    int a = at*16 + l16;
    ra[at] = (a < AA) ? rank[b*AA + a] : -1;        // -1 => always masked
  }

  float lp_part = 0.f;

  for (int it = w; it < 13; it += 4){
    bf16x8 af[4];
    {
      const u16* arow = Gbase + (size_t)(it*16 + l16)*N3;
      #pragma unroll
      for (int kb = 0; kb < 4; ++kb){
        union { uint4 u; bf16x8 v; } tmp;
        tmp.u = *(const uint4*)(arow + kb*32 + lq*8);
        af[kb] = tmp.v;
      }
    }
    f32x4 S[13];
    #pragma unroll
    for (int at = 0; at < 13; ++at){
      const u16* brow = LKbase + (size_t)(at*16 + l16)*N3;
      f32x4 acc = {0.f,0.f,0.f,0.f};
      #pragma unroll
      for (int kb = 0; kb < 4; ++kb){
        union { uint4 u; bf16x8 v; } tmp;
        tmp.u = *(const uint4*)(brow + kb*32 + lq*8);
        acc = __builtin_amdgcn_mfma_f32_16x16x32_bf16(af[kb], tmp.v, acc, 0, 0, 0);
      }
      S[at] = acc;
    }
    #pragma unroll
    for (int at = 0; at < 13; ++at)
      #pragma unroll
      for (int r = 0; r < 4; ++r){
        int i = it*16 + lq*4 + r;
        float x = S[at][r] * inv_sqrt_d;
        float e = __expf(2.0f*x);
        float th = 1.0f - 2.0f/(e + 1.0f);
        S[at][r] = (ra[at] < i) ? -__builtin_inff() : 10.0f*th;
      }
    #pragma unroll
    for (int r = 0; r < 4; ++r){
      int i = it*16 + lq*4 + r;
      float m = S[0][r];
      #pragma unroll
      for (int at = 1; at < 13; ++at) m = fmaxf(m, S[at][r]);
      #pragma unroll
      for (int off = 1; off < 16; off <<= 1) m = fmaxf(m, __shfl_xor(m, off));
      float sum = 0.f;
      #pragma unroll
      for (int at = 0; at < 13; ++at) sum += __expf(S[at][r] - m);
      #pragma unroll
      for (int off = 1; off < 16; off <<= 1) sum += __shfl_xor(sum, off);
      if (i < AA){
        float lse = m + __logf(sum);
        int act = oa[b*AA + i];
        if ((act & 15) == l16){
          int at0 = act >> 4;
          #pragma unroll
          for (int at = 0; at < 13; ++at)
            if (at == at0) lp_part += S[at][r] - lse;
        }
      }
    }
  }
  #pragma unroll
  for (int off = 1; off < 64; off <<= 1) lp_part += __shfl_xor(lp_part, off);
  if (L == 0) red[w] = lp_part;
  __syncthreads();
  if (t == 0) outlps[b] = red[0] + red[1] + red[2] + red[3];
}

// ---------------- launch ----------------
extern "C" void kernel_launch(void* const* d_in, const int* in_sizes, int n_in,
                              void* d_out, int out_size, void* d_ws, size_t ws_size,
                              hipStream_t stream){
  const float* E  = (const float*)d_in[0];
  const int*   oa = (const int*)d_in[1];
  const float* Wp = (const float*)d_in[2];
  const float* Wn = (const float*)d_in[3];
  const float* Wf = (const float*)d_in[4];
  const float* Ws = (const float*)d_in[5];
  const float* Wo = (const float*)d_in[6];
  float* out = (float*)d_out;

  char* ws = (char*)d_ws;
  int*   rank   = (int*)ws;                     //   819,200 B
  float* fixedc = (float*)(ws + 819200);        //   524,288 B
  u16*   proj   = (u16*)(ws + 1343488);         // 157,286,400 B  [B][A][384] bf16
  u16*   qhg    = (u16*)(ws + 158629888);       //  52,428,800 B  [B][A][128] bf16
  u16*   WnT    = (u16*)(ws + 211058688);       //      98,304 B  [384][128] bf16
  u16*   WsT    = (u16*)(ws + 211156992);       //      32,768 B  [128][128] bf16
  u16*   WoT    = (u16*)(ws + 211189760);       //      32,768 B  [128][128] bf16
  // total workspace: 211,222,528 B

  k_act_rank<<<dim3((BB*AA)/256), 256, 0, stream>>>(oa, out, rank);
  k_prep<<<dim3(320), 256, 0, stream>>>(Wn, Ws, Wo, WnT, WsT, WoT);
  k_fixed<<<dim3(BB), 128, 0, stream>>>(E, Wf, fixedc);
  k_proj_mfma<<<dim3((BB*AA)/128, N3/128), 256, 0, stream>>>(E, WnT, proj);
  k_query_mfma<<<dim3((BB*AA)/128), 256, 0, stream>>>(E, oa, Wp, WsT, fixedc, qhg);
  k_attn<<<dim3(BB, HH), 256, 0, stream>>>(proj, rank, qhg);
  k_glimpse_mfma<<<dim3((BB*AA)/128), 256, 0, stream>>>(qhg, WoT, proj);
  k_logits<<<dim3(BB), 256, 0, stream>>>(proj, rank, oa, out + BB*AA);
}